// Round 1
// baseline (23922.752 us; speedup 1.0000x reference)
//
#include <hip/hip_runtime.h>

// Problem constants (B=4, C=64, H=W=192)
#define HH 192
#define WID 192
#define HW (HH*WID)          // 36864
#define CB 64
#define BB 4
#define NPOS (BB*HW)         // 147456
#define NTILE (NPOS/64)      // 2304

// ---------------------------------------------------------------------------
// K1: LayerNorm over C + 1x1 conv C->2C, split into x1 (first 64) / x2 (last 64)
// ---------------------------------------------------------------------------
__global__ __launch_bounds__(256) void k_ln_conv_in(
    const float* __restrict__ x, const float* __restrict__ g, const float* __restrict__ be,
    const float* __restrict__ w_in, const float* __restrict__ b_in,
    float* __restrict__ x1, float* __restrict__ x2)
{
    int p  = blockIdx.x * 256 + threadIdx.x;     // [0, NPOS)
    int b  = p / HW;
    int hw = p % HW;
    const float* xp = x + (size_t)b * CB * HW + hw;

    float v[64];
    float sum = 0.f, sumsq = 0.f;
#pragma unroll
    for (int c = 0; c < 64; c++) {
        float t = xp[c * HW];
        v[c] = t; sum += t; sumsq += t * t;
    }
    float mu  = sum * (1.f / 64.f);
    float var = sumsq * (1.f / 64.f) - mu * mu;
    float inv = rsqrtf(var + 1e-5f);
#pragma unroll
    for (int c = 0; c < 64; c++) v[c] = (v[c] - mu) * inv * g[c] + be[c];

    float* o1 = x1 + (size_t)b * CB * HW + hw;
    float* o2 = x2 + (size_t)b * CB * HW + hw;
    for (int o = 0; o < 64; o++) {
        float a1 = b_in[o];
        float a2 = b_in[o + 64];
#pragma unroll
        for (int c = 0; c < 64; c++) {
            a1 += v[c] * w_in[o * 64 + c];
            a2 += v[c] * w_in[(o + 64) * 64 + c];
        }
        o1[o * HW] = a1;
        o2[o * HW] = a2;
    }
}

// ---------------------------------------------------------------------------
// Offset conv: KxK, pad, Cin=64 -> CO.  Block: 64 row-aligned positions x all CO.
// Thread: pg=t&15 -> 4 consecutive positions, og=t>>4 -> o in {og+16j}.
// ---------------------------------------------------------------------------
template<int K, int PAD, int CO, int NO>
__global__ __launch_bounds__(256) void k_conv(
    const float* __restrict__ xin, const float* __restrict__ w,
    const float* __restrict__ bias, float* __restrict__ out)
{
    constexpr int COLS = 64 + K - 1;
    __shared__ __align__(16) float s[4][K][72];

    int tile = blockIdx.x;
    int p0 = tile * 64;
    int b  = p0 / HW;
    int hw0 = p0 % HW;
    int y  = hw0 / WID;
    int x0 = hw0 % WID;        // tile lies in a single row (64 | 192)

    int t  = threadIdx.x;
    int pg = t & 15;
    int og = t >> 4;

    float acc[NO][4];
#pragma unroll
    for (int j = 0; j < NO; j++)
#pragma unroll
        for (int q = 0; q < 4; q++) acc[j][q] = 0.f;

    const float* xb = xin + (size_t)b * CB * HW;

    for (int c0 = 0; c0 < 64; c0 += 4) {
        __syncthreads();
        // stage 4 channel slices: K rows x COLS cols (zero-padded)
        for (int idx = t; idx < 4 * K * COLS; idx += 256) {
            int cc  = idx / (K * COLS);
            int rem = idx % (K * COLS);
            int r   = rem / COLS;
            int col = rem % COLS;
            int gy = y + r - PAD;
            int gx = x0 + col - PAD;
            float v = 0.f;
            if (gy >= 0 && gy < HH && gx >= 0 && gx < WID)
                v = xb[(size_t)(c0 + cc) * HW + gy * WID + gx];
            s[cc][r][col] = v;
        }
        __syncthreads();

#pragma unroll
        for (int cc = 0; cc < 4; cc++) {
            int c = c0 + cc;
#pragma unroll
            for (int ki = 0; ki < K; ki++) {
                // 8-wide register window over this row
                float4 a0 = *(const float4*)&s[cc][ki][pg * 4];
                float4 a1 = *(const float4*)&s[cc][ki][pg * 4 + 4];
                float r0[8] = {a0.x, a0.y, a0.z, a0.w, a1.x, a1.y, a1.z, a1.w};
#pragma unroll
                for (int kj = 0; kj < K; kj++) {
#pragma unroll
                    for (int j = 0; j < NO; j++) {
                        int o = og + 16 * j;
                        if (o < CO) {
                            float wv = w[(((size_t)o * 64 + c) * K + ki) * K + kj];
                            acc[j][0] += r0[kj + 0] * wv;
                            acc[j][1] += r0[kj + 1] * wv;
                            acc[j][2] += r0[kj + 2] * wv;
                            acc[j][3] += r0[kj + 3] * wv;
                        }
                    }
                }
            }
        }
    }

#pragma unroll
    for (int j = 0; j < NO; j++) {
        int o = og + 16 * j;
        if (o < CO) {
            float bb = bias[o];
            float* op = out + ((size_t)b * CO + o) * HW + y * WID + x0 + pg * 4;
            *(float4*)op = make_float4(acc[j][0] + bb, acc[j][1] + bb,
                                       acc[j][2] + bb, acc[j][3] + bb);
        }
    }
}

// ---------------------------------------------------------------------------
// Weight transpose for deform conv: w[o][c][k] (OIHW) -> wt[k][c][o]
// ---------------------------------------------------------------------------
__global__ void k_wt(const float* __restrict__ w, float* __restrict__ wt,
                     int KK, int total)
{
    int idx = blockIdx.x * 256 + threadIdx.x;
    if (idx < total) {
        int o = idx / (64 * KK);
        int r = idx % (64 * KK);
        int c = r / KK;
        int k = r % KK;
        wt[((size_t)k * 64 + c) * 64 + o] = w[idx];
    }
}

// ---------------------------------------------------------------------------
// Deformable conv KxK, pad; Cin=Cout=64.  Block: 64 row-aligned positions x 64 o.
// Per tap: bilinear-sample s[c][pos] into LDS, stage wt-slice, fp32 register GEMM.
// Thread (GEMM): pg=t&15 -> positions pg*4..+3, og=t>>4 -> o og*4..+3.
// Thread (sample): pos=t&63, cg=t>>6 -> channels cg*16..+15.
// ---------------------------------------------------------------------------
template<int K, int PAD>
__global__ __launch_bounds__(256) void k_dconv(
    const float* __restrict__ xin, const float* __restrict__ offp,
    const float* __restrict__ wt, const float* __restrict__ bias,
    float* __restrict__ out)
{
    constexpr int KK = K * K;
    __shared__ __align__(16) float s[64][64];
    __shared__ __align__(16) float wk[64][64];

    int tile = blockIdx.x;
    int p0 = tile * 64;
    int b  = p0 / HW;
    int hw0 = p0 % HW;
    int y  = hw0 / WID;
    int x0 = hw0 % WID;

    int t   = threadIdx.x;
    int pg  = t & 15;
    int og  = t >> 4;
    int pos = t & 63;
    int cg  = t >> 6;
    int xg  = x0 + pos;

    float acc[4][4];
#pragma unroll
    for (int j = 0; j < 4; j++)
#pragma unroll
        for (int q = 0; q < 4; q++) acc[j][q] = 0.f;

    const float* xb   = xin + (size_t)b * CB * HW;
    const float* offb = offp + (size_t)b * 2 * KK * HW + y * WID + xg;

    for (int k = 0; k < KK; k++) {
        int ki = k / K, kj = k % K;

        // ---- per-position sampling params (computed redundantly per cg) ----
        float oy = offb[(2 * k) * HW];
        float ox = offb[(2 * k + 1) * HW];
        float py = (float)(y + ki - PAD) + oy;
        float px = (float)(xg + kj - PAD) + ox;
        float fy = floorf(py), fx = floorf(px);
        float wy = py - fy, wx = px - fx;
        int iy0 = (int)fy, ix0 = (int)fx;
        int iy1 = iy0 + 1, ix1 = ix0 + 1;
        float m00 = (iy0 >= 0 && iy0 < HH && ix0 >= 0 && ix0 < WID) ? 1.f : 0.f;
        float m01 = (iy0 >= 0 && iy0 < HH && ix1 >= 0 && ix1 < WID) ? 1.f : 0.f;
        float m10 = (iy1 >= 0 && iy1 < HH && ix0 >= 0 && ix0 < WID) ? 1.f : 0.f;
        float m11 = (iy1 >= 0 && iy1 < HH && ix1 >= 0 && ix1 < WID) ? 1.f : 0.f;
        int cy0 = min(max(iy0, 0), HH - 1), cy1 = min(max(iy1, 0), HH - 1);
        int cx0 = min(max(ix0, 0), WID - 1), cx1 = min(max(ix1, 0), WID - 1);
        int i00 = cy0 * WID + cx0, i01 = cy0 * WID + cx1;
        int i10 = cy1 * WID + cx0, i11 = cy1 * WID + cx1;
        float w00 = (1.f - wy) * (1.f - wx) * m00;
        float w01 = (1.f - wy) * wx * m01;
        float w10 = wy * (1.f - wx) * m10;
        float w11 = wy * wx * m11;

        __syncthreads();   // previous GEMM reads of s/wk complete

        // ---- sample 16 channels into s[c][pos] ----
#pragma unroll
        for (int cc = 0; cc < 16; cc++) {
            int c = cg * 16 + cc;
            const float* xc = xb + (size_t)c * HW;
            float v = w00 * xc[i00] + w01 * xc[i01] + w10 * xc[i10] + w11 * xc[i11];
            s[c][pos] = v;
        }
        // ---- stage wt slice for this tap: wk[c][o] ----
        {
            const float4* src = (const float4*)(wt + (size_t)k * 4096);
            float4* dst = (float4*)&wk[0][0];
#pragma unroll
            for (int i = 0; i < 4; i++) dst[t + i * 256] = src[t + i * 256];
        }
        __syncthreads();

        // ---- register GEMM: acc[j][q] += s[c][pg*4+q] * wk[c][og*4+j] ----
#pragma unroll 8
        for (int c = 0; c < 64; c++) {
            float4 sv = *(const float4*)&s[c][pg * 4];
            float4 wv = *(const float4*)&wk[c][og * 4];
            acc[0][0] += sv.x * wv.x; acc[0][1] += sv.y * wv.x;
            acc[0][2] += sv.z * wv.x; acc[0][3] += sv.w * wv.x;
            acc[1][0] += sv.x * wv.y; acc[1][1] += sv.y * wv.y;
            acc[1][2] += sv.z * wv.y; acc[1][3] += sv.w * wv.y;
            acc[2][0] += sv.x * wv.z; acc[2][1] += sv.y * wv.z;
            acc[2][2] += sv.z * wv.z; acc[2][3] += sv.w * wv.z;
            acc[3][0] += sv.x * wv.w; acc[3][1] += sv.y * wv.w;
            acc[3][2] += sv.z * wv.w; acc[3][3] += sv.w * wv.w;
        }
    }

#pragma unroll
    for (int j = 0; j < 4; j++) {
        int o = og * 4 + j;
        float bb = bias[o];
        float* op = out + ((size_t)b * CB + o) * HW + y * WID + x0 + pg * 4;
        *(float4*)op = make_float4(acc[j][0] + bb, acc[j][1] + bb,
                                   acc[j][2] + bb, acc[j][3] + bb);
    }
}

// ---------------------------------------------------------------------------
// K4: h = x1_final + x2; out = h @ w_out^T + b_out + x (residual)
// ---------------------------------------------------------------------------
__global__ __launch_bounds__(256) void k_merge_out(
    const float* __restrict__ x1f, const float* __restrict__ x2,
    const float* __restrict__ xin, const float* __restrict__ w_out,
    const float* __restrict__ b_out, float* __restrict__ out)
{
    int p  = blockIdx.x * 256 + threadIdx.x;
    int b  = p / HW;
    int hw = p % HW;
    size_t base = (size_t)b * CB * HW + hw;

    float v[64];
#pragma unroll
    for (int c = 0; c < 64; c++) v[c] = x1f[base + c * HW] + x2[base + c * HW];

    for (int o = 0; o < 64; o++) {
        float a = b_out[o] + xin[base + o * HW];
#pragma unroll
        for (int c = 0; c < 64; c++) a += v[c] * w_out[o * 64 + c];
        out[base + o * HW] = a;
    }
}

// ---------------------------------------------------------------------------
// Launch. Workspace layout (floats):
//   x1a @ 0, x1b @ 9437184, x2 @ 18874368, off @ 28311552 (14450688 fl),
//   wt1 @ 42762240 (200704), wt2 @ 42962944 (102400), wt3 @ 43065344 (36864)
//   total = 43102208 floats = ~172.4 MB
// ---------------------------------------------------------------------------
extern "C" void kernel_launch(void* const* d_in, const int* in_sizes, int n_in,
                              void* d_out, int out_size, void* d_ws, size_t ws_size,
                              hipStream_t stream)
{
    const float* x     = (const float*)d_in[0];
    const float* ln_w  = (const float*)d_in[1];
    const float* ln_b  = (const float*)d_in[2];
    const float* w_in  = (const float*)d_in[3];
    const float* b_in  = (const float*)d_in[4];
    const float* w_out = (const float*)d_in[5];
    const float* b_out = (const float*)d_in[6];
    const float* dw1   = (const float*)d_in[7];
    const float* db1   = (const float*)d_in[8];
    const float* dw2   = (const float*)d_in[9];
    const float* db2   = (const float*)d_in[10];
    const float* dw3   = (const float*)d_in[11];
    const float* db3   = (const float*)d_in[12];
    const float* ow1   = (const float*)d_in[13];
    const float* ob1   = (const float*)d_in[14];
    const float* ow2   = (const float*)d_in[15];
    const float* ob2   = (const float*)d_in[16];
    const float* ow3   = (const float*)d_in[17];
    const float* ob3   = (const float*)d_in[18];

    float* ws = (float*)d_ws;
    const size_t TEN = (size_t)BB * CB * HW;   // 9437184
    float* x1a = ws;
    float* x1b = ws + TEN;
    float* x2  = ws + 2 * TEN;
    float* off = ws + 3 * TEN;                 // up to 4*98*HW floats
    float* wt1 = ws + 3 * TEN + (size_t)BB * 98 * HW;
    float* wt2 = wt1 + 200704;
    float* wt3 = wt2 + 102400;

    // transpose deform weights (cheap, every call)
    k_wt<<<784, 256, 0, stream>>>(dw1, wt1, 49, 200704);
    k_wt<<<400, 256, 0, stream>>>(dw2, wt2, 25, 102400);
    k_wt<<<144, 256, 0, stream>>>(dw3, wt3,  9,  36864);

    k_ln_conv_in<<<NPOS / 256, 256, 0, stream>>>(x, ln_w, ln_b, w_in, b_in, x1a, x2);

    k_conv<5, 2, 98, 7><<<NTILE, 256, 0, stream>>>(x1a, ow1, ob1, off);
    k_dconv<7, 3><<<NTILE, 256, 0, stream>>>(x1a, off, wt1, db1, x1b);

    k_conv<5, 2, 50, 4><<<NTILE, 256, 0, stream>>>(x1b, ow2, ob2, off);
    k_dconv<5, 2><<<NTILE, 256, 0, stream>>>(x1b, off, wt2, db2, x1a);

    k_conv<3, 1, 18, 2><<<NTILE, 256, 0, stream>>>(x1a, ow3, ob3, off);
    k_dconv<3, 1><<<NTILE, 256, 0, stream>>>(x1a, off, wt3, db3, x1b);

    k_merge_out<<<NPOS / 256, 256, 0, stream>>>(x1b, x2, x, w_out, b_out, (float*)d_out);
}

// Round 2
// 18113.347 us; speedup vs baseline: 1.3207x; 1.3207x over previous
//
#include <hip/hip_runtime.h>

// Problem constants (B=4, C=64, H=W=192)
#define HH 192
#define WID 192
#define HW (HH*WID)          // 36864
#define CB 64
#define BB 4
#define NPOS (BB*HW)         // 147456
#define NTILE (NPOS/64)      // 2304

// ---------------------------------------------------------------------------
// K1: LayerNorm over C + 1x1 conv C->2C, split into x1 (first 64) / x2 (last 64)
// ---------------------------------------------------------------------------
__global__ __launch_bounds__(256) void k_ln_conv_in(
    const float* __restrict__ x, const float* __restrict__ g, const float* __restrict__ be,
    const float* __restrict__ w_in, const float* __restrict__ b_in,
    float* __restrict__ x1, float* __restrict__ x2)
{
    int p  = blockIdx.x * 256 + threadIdx.x;     // [0, NPOS)
    int b  = p / HW;
    int hw = p % HW;
    const float* xp = x + (size_t)b * CB * HW + hw;

    float v[64];
    float sum = 0.f, sumsq = 0.f;
#pragma unroll
    for (int c = 0; c < 64; c++) {
        float t = xp[c * HW];
        v[c] = t; sum += t; sumsq += t * t;
    }
    float mu  = sum * (1.f / 64.f);
    float var = sumsq * (1.f / 64.f) - mu * mu;
    float inv = rsqrtf(var + 1e-5f);
#pragma unroll
    for (int c = 0; c < 64; c++) v[c] = (v[c] - mu) * inv * g[c] + be[c];

    float* o1 = x1 + (size_t)b * CB * HW + hw;
    float* o2 = x2 + (size_t)b * CB * HW + hw;
    for (int o = 0; o < 64; o++) {
        float a1 = b_in[o];
        float a2 = b_in[o + 64];
#pragma unroll
        for (int c = 0; c < 64; c++) {
            a1 += v[c] * w_in[o * 64 + c];
            a2 += v[c] * w_in[(o + 64) * 64 + c];
        }
        o1[o * HW] = a1;
        o2[o * HW] = a2;
    }
}

// ---------------------------------------------------------------------------
// Offset-conv weight transpose: w[o][c][kk] (OIHW) -> owt[c/4][kk][c&3][o],
// o padded to COP with zeros.
// ---------------------------------------------------------------------------
template<int KK, int CO, int COP>
__global__ void k_wt_off(const float* __restrict__ w, float* __restrict__ owt)
{
    int idx = blockIdx.x * 256 + threadIdx.x;
    constexpr int TOT = 64 * KK * COP;
    if (idx >= TOT) return;
    int c  = idx / (KK * COP);
    int r  = idx % (KK * COP);
    int kk = r / COP;
    int o  = r % COP;
    float v = 0.f;
    if (o < CO) v = w[((size_t)o * 64 + c) * KK + kk];
    owt[(((size_t)(c >> 2) * KK + kk) * 4 + (c & 3)) * COP + o] = v;
}

// ---------------------------------------------------------------------------
// Offset conv v2: KxK, pad, Cin=64 -> CO.  Block: 2 rows x 64 cols x CO.
// LDS: input halo chunk (4 ch) + that chunk's all-tap weights (pre-transposed).
// Thread: pg=t&15 -> 4 cols x 2 rows; og=t>>4 -> o = og*4 + 64*jj + {0..3}.
// Weights read as float4 (1 ds_read_b128 per 32 FMA) -> VALU-bound.
// ---------------------------------------------------------------------------
template<int K, int PAD, int CO, int COP, int NJ>
__global__ __launch_bounds__(256, 3) void k_oconv(
    const float* __restrict__ xin, const float* __restrict__ owt,
    const float* __restrict__ bias, float* __restrict__ out)
{
    constexpr int KK   = K * K;
    constexpr int W2   = 64 + 2 * PAD;   // valid staged cols
    constexpr int ROWS = K + 1;          // staged rows for 2 output rows
    __shared__ __align__(16) float sIn[4][ROWS][72];
    __shared__ __align__(16) float sW[4 * KK * COP];

    int bid = blockIdx.x;
    int b   = bid / (96 * 3);
    int rem = bid % (96 * 3);
    int ty  = rem / 3;
    int tx  = rem % 3;
    int y0  = ty * 2;
    int x0  = tx * 64;

    int t  = threadIdx.x;
    int pg = t & 15;
    int og = t >> 4;

    float acc[NJ][4][2][4];   // [jj][o-offset][row][col]
#pragma unroll
    for (int jj = 0; jj < NJ; jj++)
#pragma unroll
        for (int q = 0; q < 4; q++)
#pragma unroll
            for (int r = 0; r < 2; r++)
#pragma unroll
                for (int p = 0; p < 4; p++) acc[jj][q][r][p] = 0.f;

    const float* xb = xin + (size_t)b * CB * HW;

    for (int c0 = 0; c0 < 64; c0 += 4) {
        __syncthreads();
        // ---- stage input: 4 ch x ROWS x W2 (zero-padded halo) ----
        constexpr int NIN = 4 * ROWS * W2;
        for (int idx = t; idx < NIN; idx += 256) {
            int cc  = idx / (ROWS * W2);
            int r2  = idx % (ROWS * W2);
            int rr  = r2 / W2;
            int col = r2 % W2;
            int gy = y0 + rr - PAD;
            int gx = x0 + col - PAD;
            float v = 0.f;
            if (gy >= 0 && gy < HH && gx >= 0 && gx < WID)
                v = xb[(size_t)(c0 + cc) * HW + gy * WID + gx];
            sIn[cc][rr][col] = v;
        }
        // ---- stage weights: contiguous float4 memcpy of this chunk ----
        {
            constexpr int NF4 = KK * COP;   // (4*KK*COP)/4
            const float4* src = (const float4*)(owt + (size_t)(c0 >> 2) * 4 * KK * COP);
            float4* dst = (float4*)sW;
            for (int i = t; i < NF4; i += 256) dst[i] = src[i];
        }
        __syncthreads();

        for (int cc = 0; cc < 4; cc++) {
#pragma unroll
            for (int ki = 0; ki < K; ki++) {
                float rw[2][8];
#pragma unroll
                for (int r = 0; r < 2; r++) {
                    float4 a0 = *(const float4*)&sIn[cc][ki + r][pg * 4];
                    float4 a1 = *(const float4*)&sIn[cc][ki + r][pg * 4 + 4];
                    rw[r][0] = a0.x; rw[r][1] = a0.y; rw[r][2] = a0.z; rw[r][3] = a0.w;
                    rw[r][4] = a1.x; rw[r][5] = a1.y; rw[r][6] = a1.z; rw[r][7] = a1.w;
                }
#pragma unroll
                for (int kj = 0; kj < K; kj++) {
                    int kk = ki * K + kj;
#pragma unroll
                    for (int jj = 0; jj < NJ; jj++) {
                        if (jj == 0 || og * 4 + 64 * jj < CO) {
                            float4 wv = *(const float4*)&sW[(kk * 4 + cc) * COP + og * 4 + 64 * jj];
#pragma unroll
                            for (int r = 0; r < 2; r++) {
#pragma unroll
                                for (int p = 0; p < 4; p++) {
                                    float xv = rw[r][kj + p];
                                    acc[jj][0][r][p] += xv * wv.x;
                                    acc[jj][1][r][p] += xv * wv.y;
                                    acc[jj][2][r][p] += xv * wv.z;
                                    acc[jj][3][r][p] += xv * wv.w;
                                }
                            }
                        }
                    }
                }
            }
        }
    }

    // ---- write out ----
#pragma unroll
    for (int jj = 0; jj < NJ; jj++) {
#pragma unroll
        for (int q = 0; q < 4; q++) {
            int o = og * 4 + 64 * jj + q;
            if (o < CO) {
                float bb = bias[o];
#pragma unroll
                for (int r = 0; r < 2; r++) {
                    float* op = out + ((size_t)b * CO + o) * HW + (y0 + r) * WID + x0 + pg * 4;
                    *(float4*)op = make_float4(acc[jj][q][r][0] + bb, acc[jj][q][r][1] + bb,
                                               acc[jj][q][r][2] + bb, acc[jj][q][r][3] + bb);
                }
            }
        }
    }
}

// ---------------------------------------------------------------------------
// Weight transpose for deform conv: w[o][c][k] (OIHW) -> wt[k][c][o]
// ---------------------------------------------------------------------------
__global__ void k_wt(const float* __restrict__ w, float* __restrict__ wt,
                     int KK, int total)
{
    int idx = blockIdx.x * 256 + threadIdx.x;
    if (idx < total) {
        int o = idx / (64 * KK);
        int r = idx % (64 * KK);
        int c = r / KK;
        int k = r % KK;
        wt[((size_t)k * 64 + c) * 64 + o] = w[idx];
    }
}

// ---------------------------------------------------------------------------
// Deformable conv KxK, pad; Cin=Cout=64.  Block: 64 row-aligned positions x 64 o.
// ---------------------------------------------------------------------------
template<int K, int PAD>
__global__ __launch_bounds__(256) void k_dconv(
    const float* __restrict__ xin, const float* __restrict__ offp,
    const float* __restrict__ wt, const float* __restrict__ bias,
    float* __restrict__ out)
{
    constexpr int KK = K * K;
    __shared__ __align__(16) float s[64][64];
    __shared__ __align__(16) float wk[64][64];

    int tile = blockIdx.x;
    int p0 = tile * 64;
    int b  = p0 / HW;
    int hw0 = p0 % HW;
    int y  = hw0 / WID;
    int x0 = hw0 % WID;

    int t   = threadIdx.x;
    int pg  = t & 15;
    int og  = t >> 4;
    int pos = t & 63;
    int cg  = t >> 6;
    int xg  = x0 + pos;

    float acc[4][4];
#pragma unroll
    for (int j = 0; j < 4; j++)
#pragma unroll
        for (int q = 0; q < 4; q++) acc[j][q] = 0.f;

    const float* xb   = xin + (size_t)b * CB * HW;
    const float* offb = offp + (size_t)b * 2 * KK * HW + y * WID + xg;

    for (int k = 0; k < KK; k++) {
        int ki = k / K, kj = k % K;

        float oy = offb[(2 * k) * HW];
        float ox = offb[(2 * k + 1) * HW];
        float py = (float)(y + ki - PAD) + oy;
        float px = (float)(xg + kj - PAD) + ox;
        float fy = floorf(py), fx = floorf(px);
        float wy = py - fy, wx = px - fx;
        int iy0 = (int)fy, ix0 = (int)fx;
        int iy1 = iy0 + 1, ix1 = ix0 + 1;
        float m00 = (iy0 >= 0 && iy0 < HH && ix0 >= 0 && ix0 < WID) ? 1.f : 0.f;
        float m01 = (iy0 >= 0 && iy0 < HH && ix1 >= 0 && ix1 < WID) ? 1.f : 0.f;
        float m10 = (iy1 >= 0 && iy1 < HH && ix0 >= 0 && ix0 < WID) ? 1.f : 0.f;
        float m11 = (iy1 >= 0 && iy1 < HH && ix1 >= 0 && ix1 < WID) ? 1.f : 0.f;
        int cy0 = min(max(iy0, 0), HH - 1), cy1 = min(max(iy1, 0), HH - 1);
        int cx0 = min(max(ix0, 0), WID - 1), cx1 = min(max(ix1, 0), WID - 1);
        int i00 = cy0 * WID + cx0, i01 = cy0 * WID + cx1;
        int i10 = cy1 * WID + cx0, i11 = cy1 * WID + cx1;
        float w00 = (1.f - wy) * (1.f - wx) * m00;
        float w01 = (1.f - wy) * wx * m01;
        float w10 = wy * (1.f - wx) * m10;
        float w11 = wy * wx * m11;

        __syncthreads();

#pragma unroll
        for (int cc = 0; cc < 16; cc++) {
            int c = cg * 16 + cc;
            const float* xc = xb + (size_t)c * HW;
            float v = w00 * xc[i00] + w01 * xc[i01] + w10 * xc[i10] + w11 * xc[i11];
            s[c][pos] = v;
        }
        {
            const float4* src = (const float4*)(wt + (size_t)k * 4096);
            float4* dst = (float4*)&wk[0][0];
#pragma unroll
            for (int i = 0; i < 4; i++) dst[t + i * 256] = src[t + i * 256];
        }
        __syncthreads();

#pragma unroll 8
        for (int c = 0; c < 64; c++) {
            float4 sv = *(const float4*)&s[c][pg * 4];
            float4 wv = *(const float4*)&wk[c][og * 4];
            acc[0][0] += sv.x * wv.x; acc[0][1] += sv.y * wv.x;
            acc[0][2] += sv.z * wv.x; acc[0][3] += sv.w * wv.x;
            acc[1][0] += sv.x * wv.y; acc[1][1] += sv.y * wv.y;
            acc[1][2] += sv.z * wv.y; acc[1][3] += sv.w * wv.y;
            acc[2][0] += sv.x * wv.z; acc[2][1] += sv.y * wv.z;
            acc[2][2] += sv.z * wv.z; acc[2][3] += sv.w * wv.z;
            acc[3][0] += sv.x * wv.w; acc[3][1] += sv.y * wv.w;
            acc[3][2] += sv.z * wv.w; acc[3][3] += sv.w * wv.w;
        }
    }

#pragma unroll
    for (int j = 0; j < 4; j++) {
        int o = og * 4 + j;
        float bb = bias[o];
        float* op = out + ((size_t)b * CB + o) * HW + y * WID + x0 + pg * 4;
        *(float4*)op = make_float4(acc[j][0] + bb, acc[j][1] + bb,
                                   acc[j][2] + bb, acc[j][3] + bb);
    }
}

// ---------------------------------------------------------------------------
// K4: h = x1_final + x2; out = h @ w_out^T + b_out + x (residual)
// ---------------------------------------------------------------------------
__global__ __launch_bounds__(256) void k_merge_out(
    const float* __restrict__ x1f, const float* __restrict__ x2,
    const float* __restrict__ xin, const float* __restrict__ w_out,
    const float* __restrict__ b_out, float* __restrict__ out)
{
    int p  = blockIdx.x * 256 + threadIdx.x;
    int b  = p / HW;
    int hw = p % HW;
    size_t base = (size_t)b * CB * HW + hw;

    float v[64];
#pragma unroll
    for (int c = 0; c < 64; c++) v[c] = x1f[base + c * HW] + x2[base + c * HW];

    for (int o = 0; o < 64; o++) {
        float a = b_out[o] + xin[base + o * HW];
#pragma unroll
        for (int c = 0; c < 64; c++) a += v[c] * w_out[o * 64 + c];
        out[base + o * HW] = a;
    }
}

// ---------------------------------------------------------------------------
// Launch. Workspace (floats): x1a@0, x1b@TEN, x2@2TEN, off@3TEN (14,450,688),
// wt1/wt2/wt3 after off.  owt buffers are aliased into DEAD windows:
//   owt1 -> x1b head (dead until dconv1 writes it)
//   owt2 -> x1a head (dead between dconv1's last read and dconv2's write)
//   owt3 -> x1b head (dead between dconv2's last read and dconv3's write)
// ---------------------------------------------------------------------------
extern "C" void kernel_launch(void* const* d_in, const int* in_sizes, int n_in,
                              void* d_out, int out_size, void* d_ws, size_t ws_size,
                              hipStream_t stream)
{
    const float* x     = (const float*)d_in[0];
    const float* ln_w  = (const float*)d_in[1];
    const float* ln_b  = (const float*)d_in[2];
    const float* w_in  = (const float*)d_in[3];
    const float* b_in  = (const float*)d_in[4];
    const float* w_out = (const float*)d_in[5];
    const float* b_out = (const float*)d_in[6];
    const float* dw1   = (const float*)d_in[7];
    const float* db1   = (const float*)d_in[8];
    const float* dw2   = (const float*)d_in[9];
    const float* db2   = (const float*)d_in[10];
    const float* dw3   = (const float*)d_in[11];
    const float* db3   = (const float*)d_in[12];
    const float* ow1   = (const float*)d_in[13];
    const float* ob1   = (const float*)d_in[14];
    const float* ow2   = (const float*)d_in[15];
    const float* ob2   = (const float*)d_in[16];
    const float* ow3   = (const float*)d_in[17];
    const float* ob3   = (const float*)d_in[18];

    float* ws = (float*)d_ws;
    const size_t TEN = (size_t)BB * CB * HW;   // 9437184
    float* x1a = ws;
    float* x1b = ws + TEN;
    float* x2  = ws + 2 * TEN;
    float* off = ws + 3 * TEN;                 // 4*98*HW floats max
    float* wt1 = ws + 3 * TEN + (size_t)BB * 98 * HW;
    float* wt2 = wt1 + 200704;
    float* wt3 = wt2 + 102400;

    // deform weight transposes (targets are dedicated scratch)
    k_wt<<<784, 256, 0, stream>>>(dw1, wt1, 49, 200704);
    k_wt<<<400, 256, 0, stream>>>(dw2, wt2, 25, 102400);
    k_wt<<<144, 256, 0, stream>>>(dw3, wt3,  9,  36864);

    // owt1 -> x1b head (x1b untouched until dconv1)
    k_wt_off<25, 98, 104><<<650, 256, 0, stream>>>(ow1, x1b);

    k_ln_conv_in<<<NPOS / 256, 256, 0, stream>>>(x, ln_w, ln_b, w_in, b_in, x1a, x2);

    // stage 1
    k_oconv<5, 2, 98, 104, 2><<<1152, 256, 0, stream>>>(x1a, x1b, ob1, off);
    k_dconv<7, 3><<<NTILE, 256, 0, stream>>>(x1a, off, wt1, db1, x1b);

    // owt2 -> x1a head (x1a dead: last read by dconv1, rewritten by dconv2)
    k_wt_off<25, 50, 56><<<350, 256, 0, stream>>>(ow2, x1a);

    // stage 2
    k_oconv<5, 2, 50, 56, 1><<<1152, 256, 0, stream>>>(x1b, x1a, ob2, off);
    k_dconv<5, 2><<<NTILE, 256, 0, stream>>>(x1b, off, wt2, db2, x1a);

    // owt3 -> x1b head (x1b dead: last read by dconv2, rewritten by dconv3)
    k_wt_off<9, 18, 20><<<45, 256, 0, stream>>>(ow3, x1b);

    // stage 3
    k_oconv<3, 1, 18, 20, 1><<<1152, 256, 0, stream>>>(x1a, x1b, ob3, off);
    k_dconv<3, 1><<<NTILE, 256, 0, stream>>>(x1a, off, wt3, db3, x1b);

    k_merge_out<<<NPOS / 256, 256, 0, stream>>>(x1b, x2, x, w_out, b_out, (float*)d_out);
}

// Round 3
// 3828.213 us; speedup vs baseline: 6.2491x; 4.7315x over previous
//
#include <hip/hip_runtime.h>

// Problem constants (B=4, C=64, H=W=192)
#define HH 192
#define WID 192
#define HW (HH*WID)          // 36864
#define CB 64
#define BB 4
#define NPOS (BB*HW)         // 147456
#define NTILE (NPOS/64)      // 2304
#define SP 72                // LDS pitch (bf16 elems): 144B rows -> 16B aligned, bank-even

typedef __attribute__((ext_vector_type(8))) short short8;
typedef __attribute__((ext_vector_type(4))) float f32x4;

static __device__ inline unsigned short f2bf(float f) {
    union { float f; unsigned u; } a; a.f = f;
    return (unsigned short)((a.u + 0x8000u) >> 16);   // round-half-up to bf16
}

// ---------------------------------------------------------------------------
// K1: LayerNorm over C + 1x1 conv C->2C, split into x1 (first 64) / x2 (last 64)
// ---------------------------------------------------------------------------
__global__ __launch_bounds__(256) void k_ln_conv_in(
    const float* __restrict__ x, const float* __restrict__ g, const float* __restrict__ be,
    const float* __restrict__ w_in, const float* __restrict__ b_in,
    float* __restrict__ x1, float* __restrict__ x2)
{
    int p  = blockIdx.x * 256 + threadIdx.x;     // [0, NPOS)
    int b  = p / HW;
    int hw = p % HW;
    const float* xp = x + (size_t)b * CB * HW + hw;

    float v[64];
    float sum = 0.f, sumsq = 0.f;
#pragma unroll
    for (int c = 0; c < 64; c++) {
        float t = xp[c * HW];
        v[c] = t; sum += t; sumsq += t * t;
    }
    float mu  = sum * (1.f / 64.f);
    float var = sumsq * (1.f / 64.f) - mu * mu;
    float inv = rsqrtf(var + 1e-5f);
#pragma unroll
    for (int c = 0; c < 64; c++) v[c] = (v[c] - mu) * inv * g[c] + be[c];

    float* o1 = x1 + (size_t)b * CB * HW + hw;
    float* o2 = x2 + (size_t)b * CB * HW + hw;
    for (int o = 0; o < 64; o++) {
        float a1 = b_in[o];
        float a2 = b_in[o + 64];
#pragma unroll
        for (int c = 0; c < 64; c++) {
            a1 += v[c] * w_in[o * 64 + c];
            a2 += v[c] * w_in[(o + 64) * 64 + c];
        }
        o1[o * HW] = a1;
        o2[o * HW] = a2;
    }
}

// ---------------------------------------------------------------------------
// Weight prep: w[o][c][ki][kj] fp32 (OIHW) -> wt[k][o][c] bf16, o zero-padded to OP.
// ---------------------------------------------------------------------------
template<int KK, int CO, int OP>
__global__ void k_wtb(const float* __restrict__ w, unsigned short* __restrict__ wt)
{
    int idx = blockIdx.x * 256 + threadIdx.x;
    constexpr int TOT = KK * OP * 64;
    if (idx >= TOT) return;
    int k = idx / (OP * 64);
    int r = idx % (OP * 64);
    int o = r / 64;
    int c = r % 64;
    float v = (o < CO) ? w[((size_t)o * 64 + c) * KK + k] : 0.f;
    wt[idx] = f2bf(v);
}

// ---------------------------------------------------------------------------
// Unified MFMA conv kernel: per-tap GEMM  out[pos][o] += S_tap[pos][c] * W_tap[c][o]
//   DEFORM=true : S = bilinear samples at offset positions (deformable conv)
//   DEFORM=false: S = shifted input (plain conv, produces offsets)
// Block: 64 row-aligned positions (1 row x 64 cols) x OP outputs; 4 waves.
// MFMA 16x16x32 bf16: M=pos (wave w -> pos-tile w), N=o (NOT tiles), K=c (2 chunks).
// A-frags from LDS s[pos][c] (pitch SP); B-frags direct from global wt[k][o][c].
// ---------------------------------------------------------------------------
template<int K, int PAD, int NOT, int CO, bool DEFORM>
__global__ __launch_bounds__(256) void k_mconv(
    const float* __restrict__ xin, const float* __restrict__ offp,
    const unsigned short* __restrict__ wtb, const float* __restrict__ bias,
    float* __restrict__ out)
{
    constexpr int KK = K * K;
    constexpr int OP = NOT * 16;
    __shared__ __align__(16) unsigned short s[64 * SP];

    int tile = blockIdx.x;
    int p0  = tile * 64;
    int b   = p0 / HW;
    int hw0 = p0 % HW;
    int y   = hw0 / WID;
    int x0  = hw0 % WID;

    int t    = threadIdx.x;
    int lane = t & 63;
    int wave = t >> 6;
    int p    = lane & 15;    // MFMA n-index (o offset) / A m-index
    int q    = lane >> 4;    // MFMA quad
    int pos  = lane;         // sampling: position within strip
    int cg   = wave;         // sampling: 16-channel group
    int xg   = x0 + pos;

    f32x4 acc[NOT];
#pragma unroll
    for (int ot = 0; ot < NOT; ot++) acc[ot] = (f32x4){0.f, 0.f, 0.f, 0.f};

    const float* xb   = xin + (size_t)b * CB * HW;
    const float* offb = offp + (size_t)b * 2 * KK * HW + y * WID + xg;
    const float* xc0  = xb + (size_t)cg * 16 * HW;

    for (int k = 0; k < KK; k++) {
        int ki = k / K, kj = k % K;

        // ---- compute 16 sampled channel values (fp32) ----
        float vals[16];
        if (DEFORM) {
            float oy = offb[(2 * k) * HW];
            float ox = offb[(2 * k + 1) * HW];
            float py = (float)(y + ki - PAD) + oy;
            float px = (float)(xg + kj - PAD) + ox;
            float fy = floorf(py), fx = floorf(px);
            float wy = py - fy, wx = px - fx;
            int iy0 = (int)fy, ix0 = (int)fx;
            int iy1 = iy0 + 1, ix1 = ix0 + 1;
            float m00 = (iy0 >= 0 && iy0 < HH && ix0 >= 0 && ix0 < WID) ? 1.f : 0.f;
            float m01 = (iy0 >= 0 && iy0 < HH && ix1 >= 0 && ix1 < WID) ? 1.f : 0.f;
            float m10 = (iy1 >= 0 && iy1 < HH && ix0 >= 0 && ix0 < WID) ? 1.f : 0.f;
            float m11 = (iy1 >= 0 && iy1 < HH && ix1 >= 0 && ix1 < WID) ? 1.f : 0.f;
            int cy0 = min(max(iy0, 0), HH - 1), cy1 = min(max(iy1, 0), HH - 1);
            int cx0 = min(max(ix0, 0), WID - 1), cx1 = min(max(ix1, 0), WID - 1);
            int i00 = cy0 * WID + cx0, i01 = cy0 * WID + cx1;
            int i10 = cy1 * WID + cx0, i11 = cy1 * WID + cx1;
            float w00 = (1.f - wy) * (1.f - wx) * m00;
            float w01 = (1.f - wy) * wx * m01;
            float w10 = wy * (1.f - wx) * m10;
            float w11 = wy * wx * m11;
            const float* xc = xc0;
#pragma unroll
            for (int cc = 0; cc < 16; cc++) {
                vals[cc] = w00 * xc[i00] + w01 * xc[i01] + w10 * xc[i10] + w11 * xc[i11];
                xc += HW;
            }
        } else {
            int gy = y + ki - PAD;
            int gx = xg + kj - PAD;
            bool ok = (gy >= 0 && gy < HH && gx >= 0 && gx < WID);
            const float* xc = xc0 + (ok ? (gy * WID + gx) : 0);
#pragma unroll
            for (int cc = 0; cc < 16; cc++)
                vals[cc] = ok ? xc[(size_t)cc * HW] : 0.f;
        }

        __syncthreads();   // previous tap's A-frag reads done
        {
            short8 v0, v1;
#pragma unroll
            for (int i = 0; i < 8; i++) {
                v0[i] = (short)f2bf(vals[i]);
                v1[i] = (short)f2bf(vals[i + 8]);
            }
            *(short8*)&s[pos * SP + cg * 16]     = v0;
            *(short8*)&s[pos * SP + cg * 16 + 8] = v1;
        }
        __syncthreads();

        // ---- MFMA: wave's 16-pos tile x all o-tiles, K=64 in 2 chunks ----
        const short8* wp = (const short8*)(wtb + (size_t)k * OP * 64);
#pragma unroll
        for (int ch = 0; ch < 2; ch++) {
            short8 a = *(const short8*)&s[(wave * 16 + p) * SP + ch * 32 + q * 8];
#pragma unroll
            for (int ot = 0; ot < NOT; ot++) {
                int o = ot * 16 + p;
                short8 bf = wp[(size_t)o * 8 + ch * 4 + q];
                acc[ot] = __builtin_amdgcn_mfma_f32_16x16x32_bf16(a, bf, acc[ot], 0, 0, 0);
            }
        }
    }

    // ---- epilogue: D reg i -> pos = wave*16 + q*4 + i, o = ot*16 + p ----
#pragma unroll
    for (int ot = 0; ot < NOT; ot++) {
        int o = ot * 16 + p;
        if (CO == OP || o < CO) {
            float bb = bias[o];
            float* op = out + ((size_t)b * CO + o) * HW + y * WID + x0 + wave * 16 + q * 4;
            *(float4*)op = make_float4(acc[ot][0] + bb, acc[ot][1] + bb,
                                       acc[ot][2] + bb, acc[ot][3] + bb);
        }
    }
}

// ---------------------------------------------------------------------------
// K4: h = x1_final + x2; out = h @ w_out^T + b_out + x (residual)
// ---------------------------------------------------------------------------
__global__ __launch_bounds__(256) void k_merge_out(
    const float* __restrict__ x1f, const float* __restrict__ x2,
    const float* __restrict__ xin, const float* __restrict__ w_out,
    const float* __restrict__ b_out, float* __restrict__ out)
{
    int p  = blockIdx.x * 256 + threadIdx.x;
    int b  = p / HW;
    int hw = p % HW;
    size_t base = (size_t)b * CB * HW + hw;

    float v[64];
#pragma unroll
    for (int c = 0; c < 64; c++) v[c] = x1f[base + c * HW] + x2[base + c * HW];

    for (int o = 0; o < 64; o++) {
        float a = b_out[o] + xin[base + o * HW];
#pragma unroll
        for (int c = 0; c < 64; c++) a += v[c] * w_out[o * 64 + c];
        out[base + o * HW] = a;
    }
}

// ---------------------------------------------------------------------------
// Launch. Workspace (floats): x1a@0, x1b@TEN, x2@2TEN, off@3TEN (BB*98*HW fl),
// then bf16 weight buffers (~1.3 MB total).
// ---------------------------------------------------------------------------
extern "C" void kernel_launch(void* const* d_in, const int* in_sizes, int n_in,
                              void* d_out, int out_size, void* d_ws, size_t ws_size,
                              hipStream_t stream)
{
    const float* x     = (const float*)d_in[0];
    const float* ln_w  = (const float*)d_in[1];
    const float* ln_b  = (const float*)d_in[2];
    const float* w_in  = (const float*)d_in[3];
    const float* b_in  = (const float*)d_in[4];
    const float* w_out = (const float*)d_in[5];
    const float* b_out = (const float*)d_in[6];
    const float* dw1   = (const float*)d_in[7];
    const float* db1   = (const float*)d_in[8];
    const float* dw2   = (const float*)d_in[9];
    const float* db2   = (const float*)d_in[10];
    const float* dw3   = (const float*)d_in[11];
    const float* db3   = (const float*)d_in[12];
    const float* ow1   = (const float*)d_in[13];
    const float* ob1   = (const float*)d_in[14];
    const float* ow2   = (const float*)d_in[15];
    const float* ob2   = (const float*)d_in[16];
    const float* ow3   = (const float*)d_in[17];
    const float* ob3   = (const float*)d_in[18];

    float* ws = (float*)d_ws;
    const size_t TEN = (size_t)BB * CB * HW;   // 9437184
    float* x1a = ws;
    float* x1b = ws + TEN;
    float* x2  = ws + 2 * TEN;
    float* off = ws + 3 * TEN;                 // BB*98*HW floats max

    unsigned short* wtd1 = (unsigned short*)(ws + 3 * TEN + (size_t)BB * 98 * HW);
    unsigned short* wtd2 = wtd1 + 49 * 64 * 64;    // +200704
    unsigned short* wtd3 = wtd2 + 25 * 64 * 64;    // +102400
    unsigned short* wto1 = wtd3 +  9 * 64 * 64;    // +36864
    unsigned short* wto2 = wto1 + 25 * 112 * 64;   // +179200
    unsigned short* wto3 = wto2 + 25 * 64 * 64;    // +102400

    // weight prep (bf16, [tap][o][c])
    k_wtb<49, 64,  64><<<784, 256, 0, stream>>>(dw1, wtd1);
    k_wtb<25, 64,  64><<<400, 256, 0, stream>>>(dw2, wtd2);
    k_wtb< 9, 64,  64><<<144, 256, 0, stream>>>(dw3, wtd3);
    k_wtb<25, 98, 112><<<700, 256, 0, stream>>>(ow1, wto1);
    k_wtb<25, 50,  64><<<400, 256, 0, stream>>>(ow2, wto2);
    k_wtb< 9, 18,  32><<< 72, 256, 0, stream>>>(ow3, wto3);

    k_ln_conv_in<<<NPOS / 256, 256, 0, stream>>>(x, ln_w, ln_b, w_in, b_in, x1a, x2);

    // stage 1
    k_mconv<5, 2, 7, 98, false><<<NTILE, 256, 0, stream>>>(x1a, x1a, wto1, ob1, off);
    k_mconv<7, 3, 4, 64, true ><<<NTILE, 256, 0, stream>>>(x1a, off, wtd1, db1, x1b);
    // stage 2
    k_mconv<5, 2, 4, 50, false><<<NTILE, 256, 0, stream>>>(x1b, x1b, wto2, ob2, off);
    k_mconv<5, 2, 4, 64, true ><<<NTILE, 256, 0, stream>>>(x1b, off, wtd2, db2, x1a);
    // stage 3
    k_mconv<3, 1, 2, 18, false><<<NTILE, 256, 0, stream>>>(x1a, x1a, wto3, ob3, off);
    k_mconv<3, 1, 4, 64, true ><<<NTILE, 256, 0, stream>>>(x1a, off, wtd3, db3, x1b);

    k_merge_out<<<NPOS / 256, 256, 0, stream>>>(x1b, x2, x, w_out, b_out, (float*)d_out);
}

// Round 4
// 2571.092 us; speedup vs baseline: 9.3045x; 1.4889x over previous
//
#include <hip/hip_runtime.h>

// Problem constants (B=4, C=64, H=W=192)
#define HH 192
#define WID 192
#define HW (HH*WID)          // 36864
#define CB 64
#define BB 4
#define NPOS (BB*HW)         // 147456
#define NTILE (NPOS/64)      // 2304
#define SP 72                // LDS pitch (bf16 elems): 144 B rows

typedef __attribute__((ext_vector_type(8))) short short8;
typedef __attribute__((ext_vector_type(8))) unsigned short ushort8;
typedef __attribute__((ext_vector_type(4))) unsigned short ushort4v;
typedef __attribute__((ext_vector_type(4))) float f32x4;

static __device__ inline unsigned short f2bf(float f) {
    union { float f; unsigned u; } a; a.f = f;
    return (unsigned short)((a.u + 0x8000u) >> 16);   // round-half-up to bf16
}
static __device__ inline float bf2f(unsigned short h) {
    union { unsigned u; float f; } a; a.u = ((unsigned)h) << 16;
    return a.f;
}

// ---------------------------------------------------------------------------
// K1: LayerNorm over C + 1x1 conv C->2C; outputs x1/x2 in NHWC bf16.
// ---------------------------------------------------------------------------
__global__ __launch_bounds__(256) void k_ln_conv_in(
    const float* __restrict__ x, const float* __restrict__ g, const float* __restrict__ be,
    const float* __restrict__ w_in, const float* __restrict__ b_in,
    unsigned short* __restrict__ x1, unsigned short* __restrict__ x2)
{
    int p  = blockIdx.x * 256 + threadIdx.x;     // [0, NPOS)
    int b  = p / HW;
    int hw = p % HW;
    const float* xp = x + (size_t)b * CB * HW + hw;

    float v[64];
    float sum = 0.f, sumsq = 0.f;
#pragma unroll
    for (int c = 0; c < 64; c++) {
        float t = xp[c * HW];
        v[c] = t; sum += t; sumsq += t * t;
    }
    float mu  = sum * (1.f / 64.f);
    float var = sumsq * (1.f / 64.f) - mu * mu;
    float inv = rsqrtf(var + 1e-5f);
#pragma unroll
    for (int c = 0; c < 64; c++) v[c] = (v[c] - mu) * inv * g[c] + be[c];

    unsigned short* o1 = x1 + (size_t)p * 64;
    unsigned short* o2 = x2 + (size_t)p * 64;
    for (int o8 = 0; o8 < 8; o8++) {
        ushort8 r1, r2;
#pragma unroll
        for (int j = 0; j < 8; j++) {
            int o = o8 * 8 + j;
            float a1 = b_in[o];
            float a2 = b_in[o + 64];
#pragma unroll
            for (int c = 0; c < 64; c++) {
                a1 += v[c] * w_in[o * 64 + c];
                a2 += v[c] * w_in[(o + 64) * 64 + c];
            }
            r1[j] = f2bf(a1);
            r2[j] = f2bf(a2);
        }
        *(ushort8*)&o1[o8 * 8] = r1;
        *(ushort8*)&o2[o8 * 8] = r2;
    }
}

// ---------------------------------------------------------------------------
// Weight prep: w[o][c][ki][kj] fp32 (OIHW) -> wt[k][o][c] bf16, o padded to OP.
// ---------------------------------------------------------------------------
template<int KK, int CO, int OP>
__global__ void k_wtb(const float* __restrict__ w, unsigned short* __restrict__ wt)
{
    int idx = blockIdx.x * 256 + threadIdx.x;
    constexpr int TOT = KK * OP * 64;
    if (idx >= TOT) return;
    int k = idx / (OP * 64);
    int r = idx % (OP * 64);
    int o = r / 64;
    int c = r % 64;
    float v = (o < CO) ? w[((size_t)o * 64 + c) * KK + k] : 0.f;
    wt[idx] = f2bf(v);
}

// ---------------------------------------------------------------------------
// Unified MFMA conv kernel (NHWC bf16 input):
//   per-tap GEMM  out[o][pos] tile via MFMA D = W(o,c) * S(c,pos)
//   DEFORM=true : S = bilinear samples; out = bf16 NHWC pitch 64; PITCH = off pitch (in)
//   DEFORM=false: S = shifted input;    out = fp32 NHWC pitch PITCH (offsets)
// Block: 64 row-aligned positions x OP outputs; 4 waves (wave = 16-pos tile / cg group).
// A-frag (weights, m=o) direct from global wt[k][o][c]; B-frag (samples, n=pos) from LDS.
// D: lane p -> pos wave*16+p; rows q*4+i -> o = ot*16+q*4+i (contiguous channel store).
// ---------------------------------------------------------------------------
template<int K, int PAD, int NOT, int CO, int PITCH, bool DEFORM>
__global__ __launch_bounds__(256) void k_mconv(
    const unsigned short* __restrict__ xin, const float* __restrict__ offp,
    const unsigned short* __restrict__ wtb, const float* __restrict__ bias,
    void* __restrict__ outv)
{
    constexpr int KK = K * K;
    constexpr int OP = NOT * 16;
    __shared__ __align__(16) unsigned short s[64 * SP];

    int tile = blockIdx.x;
    int p0  = tile * 64;
    int b   = p0 / HW;
    int hw0 = p0 % HW;
    int y   = hw0 / WID;
    int x0  = hw0 % WID;

    int t    = threadIdx.x;
    int lane = t & 63;
    int wave = t >> 6;
    int p    = lane & 15;
    int q    = lane >> 4;
    int pos  = lane;
    int cg   = wave;
    int xg   = x0 + pos;

    f32x4 acc[NOT];
#pragma unroll
    for (int ot = 0; ot < NOT; ot++) acc[ot] = (f32x4){0.f, 0.f, 0.f, 0.f};

    const unsigned short* xb = xin + (size_t)b * HW * 64;     // image base, NHWC
    const float* offb = offp + ((size_t)p0 + pos) * PITCH;    // this position's offsets

    for (int k = 0; k < KK; k++) {
        int ki = k / K, kj = k % K;

        ushort8 sv0, sv1;   // 16 bf16 channel values for (pos, tap)
        if (DEFORM) {
            float oy = offb[2 * k];
            float ox = offb[2 * k + 1];
            float py = (float)(y + ki - PAD) + oy;
            float px = (float)(xg + kj - PAD) + ox;
            float fy = floorf(py), fx = floorf(px);
            float wy = py - fy, wx = px - fx;
            int iy0 = (int)fy, ix0 = (int)fx;
            int iy1 = iy0 + 1, ix1 = ix0 + 1;
            float m00 = (iy0 >= 0 && iy0 < HH && ix0 >= 0 && ix0 < WID) ? 1.f : 0.f;
            float m01 = (iy0 >= 0 && iy0 < HH && ix1 >= 0 && ix1 < WID) ? 1.f : 0.f;
            float m10 = (iy1 >= 0 && iy1 < HH && ix0 >= 0 && ix0 < WID) ? 1.f : 0.f;
            float m11 = (iy1 >= 0 && iy1 < HH && ix1 >= 0 && ix1 < WID) ? 1.f : 0.f;
            int cy0 = min(max(iy0, 0), HH - 1), cy1 = min(max(iy1, 0), HH - 1);
            int cx0 = min(max(ix0, 0), WID - 1), cx1 = min(max(ix1, 0), WID - 1);
            float w00 = (1.f - wy) * (1.f - wx) * m00;
            float w01 = (1.f - wy) * wx * m01;
            float w10 = wy * (1.f - wx) * m10;
            float w11 = wy * wx * m11;
            const unsigned short* c00 = xb + ((size_t)(cy0 * WID + cx0)) * 64 + cg * 16;
            const unsigned short* c01 = xb + ((size_t)(cy0 * WID + cx1)) * 64 + cg * 16;
            const unsigned short* c10 = xb + ((size_t)(cy1 * WID + cx0)) * 64 + cg * 16;
            const unsigned short* c11 = xb + ((size_t)(cy1 * WID + cx1)) * 64 + cg * 16;
            ushort8 a00 = *(const ushort8*)c00, b00 = *(const ushort8*)(c00 + 8);
            ushort8 a01 = *(const ushort8*)c01, b01 = *(const ushort8*)(c01 + 8);
            ushort8 a10 = *(const ushort8*)c10, b10 = *(const ushort8*)(c10 + 8);
            ushort8 a11 = *(const ushort8*)c11, b11 = *(const ushort8*)(c11 + 8);
#pragma unroll
            for (int cc = 0; cc < 8; cc++) {
                float v0 = w00 * bf2f(a00[cc]) + w01 * bf2f(a01[cc])
                         + w10 * bf2f(a10[cc]) + w11 * bf2f(a11[cc]);
                float v1 = w00 * bf2f(b00[cc]) + w01 * bf2f(b01[cc])
                         + w10 * bf2f(b10[cc]) + w11 * bf2f(b11[cc]);
                sv0[cc] = f2bf(v0);
                sv1[cc] = f2bf(v1);
            }
        } else {
            int gy = y + ki - PAD;
            int gx = xg + kj - PAD;
            bool ok = (gy >= 0 && gy < HH && gx >= 0 && gx < WID);
            if (ok) {
                const unsigned short* cp = xb + ((size_t)(gy * WID + gx)) * 64 + cg * 16;
                sv0 = *(const ushort8*)cp;
                sv1 = *(const ushort8*)(cp + 8);
            } else {
                sv0 = 0; sv1 = 0;
            }
        }

        __syncthreads();   // previous tap's B-frag reads done
        *(ushort8*)&s[pos * SP + cg * 16]     = sv0;
        *(ushort8*)&s[pos * SP + cg * 16 + 8] = sv1;
        __syncthreads();

        // ---- MFMA: A=weights (m=o), B=samples (n=pos), K=64 in 2 chunks ----
        const short8* wp = (const short8*)(wtb + (size_t)k * OP * 64);
#pragma unroll
        for (int ch = 0; ch < 2; ch++) {
            short8 bfrag = *(const short8*)&s[(wave * 16 + p) * SP + ch * 32 + q * 8];
#pragma unroll
            for (int ot = 0; ot < NOT; ot++) {
                short8 afrag = wp[(size_t)(ot * 16 + p) * 8 + ch * 4 + q];
                acc[ot] = __builtin_amdgcn_mfma_f32_16x16x32_bf16(afrag, bfrag, acc[ot], 0, 0, 0);
            }
        }
    }

    // ---- epilogue: pos = p0 + wave*16 + p; o = ot*16 + q*4 + i ----
    size_t opos = (size_t)p0 + wave * 16 + p;
#pragma unroll
    for (int ot = 0; ot < NOT; ot++) {
        int ob = ot * 16 + q * 4;
        if (DEFORM) {
            unsigned short* outp = (unsigned short*)outv;
            float4 bb = *(const float4*)&bias[ob];
            ushort4v r;
            r[0] = f2bf(acc[ot][0] + bb.x);
            r[1] = f2bf(acc[ot][1] + bb.y);
            r[2] = f2bf(acc[ot][2] + bb.z);
            r[3] = f2bf(acc[ot][3] + bb.w);
            *(ushort4v*)&outp[opos * 64 + ob] = r;
        } else {
            if (ob + 4 <= PITCH) {
                float* outf = (float*)outv;
                float b0 = bias[min(ob + 0, CO - 1)];
                float b1 = bias[min(ob + 1, CO - 1)];
                float b2 = bias[min(ob + 2, CO - 1)];
                float b3 = bias[min(ob + 3, CO - 1)];
                *(float4*)&outf[opos * PITCH + ob] =
                    make_float4(acc[ot][0] + b0, acc[ot][1] + b1,
                                acc[ot][2] + b2, acc[ot][3] + b3);
            }
        }
    }
}

// ---------------------------------------------------------------------------
// K4: h = x1_final + x2 (NHWC bf16); out = h @ w_out^T + b_out + x (NCHW fp32)
// ---------------------------------------------------------------------------
__global__ __launch_bounds__(256) void k_merge_out(
    const unsigned short* __restrict__ x1f, const unsigned short* __restrict__ x2,
    const float* __restrict__ xin, const float* __restrict__ w_out,
    const float* __restrict__ b_out, float* __restrict__ out)
{
    int p  = blockIdx.x * 256 + threadIdx.x;
    int b  = p / HW;
    int hw = p % HW;

    const unsigned short* a1 = x1f + (size_t)p * 64;
    const unsigned short* a2 = x2  + (size_t)p * 64;
    float v[64];
#pragma unroll
    for (int c8 = 0; c8 < 8; c8++) {
        ushort8 u1 = *(const ushort8*)&a1[c8 * 8];
        ushort8 u2 = *(const ushort8*)&a2[c8 * 8];
#pragma unroll
        for (int j = 0; j < 8; j++)
            v[c8 * 8 + j] = bf2f(u1[j]) + bf2f(u2[j]);
    }

    size_t base = (size_t)b * CB * HW + hw;
    for (int o = 0; o < 64; o++) {
        float a = b_out[o] + xin[base + (size_t)o * HW];
#pragma unroll
        for (int c = 0; c < 64; c++) a += v[c] * w_out[o * 64 + c];
        out[base + (size_t)o * HW] = a;
    }
}

// ---------------------------------------------------------------------------
// Launch. Workspace (bytes):
//   x1a/x1b/x2: NPOS*64 bf16 each (18,874,368 B each)
//   off: NPOS*100 fp32 (58,982,400 B)
//   weight buffers bf16 (~1.28 MB)     total ~112 MB
// ---------------------------------------------------------------------------
extern "C" void kernel_launch(void* const* d_in, const int* in_sizes, int n_in,
                              void* d_out, int out_size, void* d_ws, size_t ws_size,
                              hipStream_t stream)
{
    const float* x     = (const float*)d_in[0];
    const float* ln_w  = (const float*)d_in[1];
    const float* ln_b  = (const float*)d_in[2];
    const float* w_in  = (const float*)d_in[3];
    const float* b_in  = (const float*)d_in[4];
    const float* w_out = (const float*)d_in[5];
    const float* b_out = (const float*)d_in[6];
    const float* dw1   = (const float*)d_in[7];
    const float* db1   = (const float*)d_in[8];
    const float* dw2   = (const float*)d_in[9];
    const float* db2   = (const float*)d_in[10];
    const float* dw3   = (const float*)d_in[11];
    const float* db3   = (const float*)d_in[12];
    const float* ow1   = (const float*)d_in[13];
    const float* ob1   = (const float*)d_in[14];
    const float* ow2   = (const float*)d_in[15];
    const float* ob2   = (const float*)d_in[16];
    const float* ow3   = (const float*)d_in[17];
    const float* ob3   = (const float*)d_in[18];

    unsigned short* x1a = (unsigned short*)d_ws;
    unsigned short* x1b = x1a + (size_t)NPOS * 64;
    unsigned short* x2  = x1b + (size_t)NPOS * 64;
    float* off = (float*)(x2 + (size_t)NPOS * 64);
    unsigned short* wtd1 = (unsigned short*)(off + (size_t)NPOS * 100);
    unsigned short* wtd2 = wtd1 + 49 * 64 * 64;
    unsigned short* wtd3 = wtd2 + 25 * 64 * 64;
    unsigned short* wto1 = wtd3 +  9 * 64 * 64;
    unsigned short* wto2 = wto1 + 25 * 112 * 64;
    unsigned short* wto3 = wto2 + 25 * 64 * 64;

    // weight prep (bf16, [tap][o][c])
    k_wtb<49, 64,  64><<<784, 256, 0, stream>>>(dw1, wtd1);
    k_wtb<25, 64,  64><<<400, 256, 0, stream>>>(dw2, wtd2);
    k_wtb< 9, 64,  64><<<144, 256, 0, stream>>>(dw3, wtd3);
    k_wtb<25, 98, 112><<<700, 256, 0, stream>>>(ow1, wto1);
    k_wtb<25, 50,  64><<<400, 256, 0, stream>>>(ow2, wto2);
    k_wtb< 9, 18,  32><<< 72, 256, 0, stream>>>(ow3, wto3);

    k_ln_conv_in<<<NPOS / 256, 256, 0, stream>>>(x, ln_w, ln_b, w_in, b_in, x1a, x2);

    // stage 1 (off pitch 100)
    k_mconv<5, 2, 7, 98, 100, false><<<NTILE, 256, 0, stream>>>(x1a, off, wto1, ob1, off);
    k_mconv<7, 3, 4, 64, 100, true ><<<NTILE, 256, 0, stream>>>(x1a, off, wtd1, db1, x1b);
    // stage 2 (off pitch 52)
    k_mconv<5, 2, 4, 50,  52, false><<<NTILE, 256, 0, stream>>>(x1b, off, wto2, ob2, off);
    k_mconv<5, 2, 4, 64,  52, true ><<<NTILE, 256, 0, stream>>>(x1b, off, wtd2, db2, x1a);
    // stage 3 (off pitch 20)
    k_mconv<3, 1, 2, 18,  20, false><<<NTILE, 256, 0, stream>>>(x1a, off, wto3, ob3, off);
    k_mconv<3, 1, 4, 64,  20, true ><<<NTILE, 256, 0, stream>>>(x1a, off, wtd3, db3, x1b);

    k_merge_out<<<NPOS / 256, 256, 0, stream>>>(x1b, x2, x, w_out, b_out, (float*)d_out);
}

// Round 5
// 2461.188 us; speedup vs baseline: 9.7200x; 1.0447x over previous
//
#include <hip/hip_runtime.h>

// Problem constants (B=4, C=64, H=W=192)
#define HH 192
#define WID 192
#define HW (HH*WID)          // 36864
#define CB 64
#define BB 4
#define NPOS (BB*HW)         // 147456
#define NTILE (NPOS/64)      // 2304

typedef __attribute__((ext_vector_type(8))) short short8;
typedef __attribute__((ext_vector_type(8))) unsigned short ushort8;
typedef __attribute__((ext_vector_type(4))) unsigned short ushort4v;
typedef __attribute__((ext_vector_type(4))) float f32x4;

static __device__ inline unsigned short f2bf(float f) {
    union { float f; unsigned u; } a; a.f = f;
    return (unsigned short)((a.u + 0x8000u) >> 16);   // round-half-up to bf16
}
static __device__ inline float bf2f(unsigned short h) {
    union { unsigned u; float f; } a; a.u = ((unsigned)h) << 16;
    return a.f;
}

// ---------------------------------------------------------------------------
// K1: LayerNorm over C + 1x1 conv C->2C; outputs x1/x2 in NHWC bf16.
// ---------------------------------------------------------------------------
__global__ __launch_bounds__(256) void k_ln_conv_in(
    const float* __restrict__ x, const float* __restrict__ g, const float* __restrict__ be,
    const float* __restrict__ w_in, const float* __restrict__ b_in,
    unsigned short* __restrict__ x1, unsigned short* __restrict__ x2)
{
    int p  = blockIdx.x * 256 + threadIdx.x;     // [0, NPOS)
    int b  = p / HW;
    int hw = p % HW;
    const float* xp = x + (size_t)b * CB * HW + hw;

    float v[64];
    float sum = 0.f, sumsq = 0.f;
#pragma unroll
    for (int c = 0; c < 64; c++) {
        float t = xp[c * HW];
        v[c] = t; sum += t; sumsq += t * t;
    }
    float mu  = sum * (1.f / 64.f);
    float var = sumsq * (1.f / 64.f) - mu * mu;
    float inv = rsqrtf(var + 1e-5f);
#pragma unroll
    for (int c = 0; c < 64; c++) v[c] = (v[c] - mu) * inv * g[c] + be[c];

    unsigned short* o1 = x1 + (size_t)p * 64;
    unsigned short* o2 = x2 + (size_t)p * 64;
    for (int o8 = 0; o8 < 8; o8++) {
        ushort8 r1, r2;
#pragma unroll
        for (int j = 0; j < 8; j++) {
            int o = o8 * 8 + j;
            float a1 = b_in[o];
            float a2 = b_in[o + 64];
#pragma unroll
            for (int c = 0; c < 64; c++) {
                a1 += v[c] * w_in[o * 64 + c];
                a2 += v[c] * w_in[(o + 64) * 64 + c];
            }
            r1[j] = f2bf(a1);
            r2[j] = f2bf(a2);
        }
        *(ushort8*)&o1[o8 * 8] = r1;
        *(ushort8*)&o2[o8 * 8] = r2;
    }
}

// ---------------------------------------------------------------------------
// Weight prep: w[o][c][ki][kj] fp32 (OIHW) -> wt[k][o][c] bf16, o padded to OP.
// ---------------------------------------------------------------------------
template<int KK, int CO, int OP>
__global__ void k_wtb(const float* __restrict__ w, unsigned short* __restrict__ wt)
{
    int idx = blockIdx.x * 256 + threadIdx.x;
    constexpr int TOT = KK * OP * 64;
    if (idx >= TOT) return;
    int k = idx / (OP * 64);
    int r = idx % (OP * 64);
    int o = r / 64;
    int c = r % 64;
    float v = (o < CO) ? w[((size_t)o * 64 + c) * KK + k] : 0.f;
    wt[idx] = f2bf(v);
}

// ---------------------------------------------------------------------------
// Barrier-free wave-local MFMA conv (NHWC bf16 input).
// Per-tap GEMM: D(o,pos) += W(o,c) * S(c,pos), MFMA 16x16x32 bf16.
// Block = 64 row-aligned positions, 4 waves; wave w owns positions w*16..+15.
// Lane l: p = l&15 (position/n and o-row/m), q = l>>4 (K-quad).
// B-frag computed IN REGISTERS: lane l needs S[c = ch*32+q*8 .. +7][pos p]
//   = one 16B NHWC load per corner per chunk. No LDS, no __syncthreads.
// A-frag direct from global wt[k][o][c] (L1/L2-hot).
// DEFORM=true : bilinear sampling via offp (pitch PITCH); out bf16 NHWC pitch 64.
// DEFORM=false: shifted-window sampling; out fp32 NHWC pitch PITCH (offsets).
// ---------------------------------------------------------------------------
template<int K, int PAD, int NOT, int CO, int PITCH, bool DEFORM>
__global__ __launch_bounds__(256) void k_mconv(
    const unsigned short* __restrict__ xin, const float* __restrict__ offp,
    const unsigned short* __restrict__ wtb, const float* __restrict__ bias,
    void* __restrict__ outv)
{
    constexpr int KK = K * K;
    constexpr int OP = NOT * 16;

    int tile = blockIdx.x;
    int p0  = tile * 64;
    int b   = p0 / HW;
    int hw0 = p0 % HW;
    int y   = hw0 / WID;
    int x0  = hw0 % WID;

    int t    = threadIdx.x;
    int lane = t & 63;
    int wave = t >> 6;
    int p    = lane & 15;
    int q    = lane >> 4;
    int q8   = q * 8;
    int xg   = x0 + wave * 16 + p;    // this lane's position (column)

    f32x4 acc[NOT];
#pragma unroll
    for (int ot = 0; ot < NOT; ot++) acc[ot] = (f32x4){0.f, 0.f, 0.f, 0.f};

    const unsigned short* xb = xin + (size_t)b * HW * 64;               // NHWC image base
    const float* offb = offp + ((size_t)p0 + wave * 16 + p) * PITCH;    // lane's offsets

    float2 offcur;
    if (DEFORM) offcur = *(const float2*)&offb[0];

    for (int k = 0; k < KK; k++) {
        int ki = k / K, kj = k % K;

        short8 bf0, bf1;   // B-frags for the two 32-wide K-chunks
        if (DEFORM) {
            float oy = offcur.x;
            float ox = offcur.y;
            if (k + 1 < KK) offcur = *(const float2*)&offb[2 * (k + 1)];  // prefetch
            float py = (float)(y + ki - PAD) + oy;
            float px = (float)(xg + kj - PAD) + ox;
            float fy = floorf(py), fx = floorf(px);
            float wy = py - fy, wx = px - fx;
            int iy0 = (int)fy, ix0 = (int)fx;
            int iy1 = iy0 + 1, ix1 = ix0 + 1;
            float m00 = (iy0 >= 0 && iy0 < HH && ix0 >= 0 && ix0 < WID) ? 1.f : 0.f;
            float m01 = (iy0 >= 0 && iy0 < HH && ix1 >= 0 && ix1 < WID) ? 1.f : 0.f;
            float m10 = (iy1 >= 0 && iy1 < HH && ix0 >= 0 && ix0 < WID) ? 1.f : 0.f;
            float m11 = (iy1 >= 0 && iy1 < HH && ix1 >= 0 && ix1 < WID) ? 1.f : 0.f;
            int cy0 = min(max(iy0, 0), HH - 1), cy1 = min(max(iy1, 0), HH - 1);
            int cx0 = min(max(ix0, 0), WID - 1), cx1 = min(max(ix1, 0), WID - 1);
            float w00 = (1.f - wy) * (1.f - wx) * m00;
            float w01 = (1.f - wy) * wx * m01;
            float w10 = wy * (1.f - wx) * m10;
            float w11 = wy * wx * m11;
            const unsigned short* c00 = xb + ((size_t)(cy0 * WID + cx0)) * 64 + q8;
            const unsigned short* c01 = xb + ((size_t)(cy0 * WID + cx1)) * 64 + q8;
            const unsigned short* c10 = xb + ((size_t)(cy1 * WID + cx0)) * 64 + q8;
            const unsigned short* c11 = xb + ((size_t)(cy1 * WID + cx1)) * 64 + q8;
            ushort8 a00 = *(const ushort8*)c00, b00 = *(const ushort8*)(c00 + 32);
            ushort8 a01 = *(const ushort8*)c01, b01 = *(const ushort8*)(c01 + 32);
            ushort8 a10 = *(const ushort8*)c10, b10 = *(const ushort8*)(c10 + 32);
            ushort8 a11 = *(const ushort8*)c11, b11 = *(const ushort8*)(c11 + 32);
#pragma unroll
            for (int j = 0; j < 8; j++) {
                float v0 = w00 * bf2f(a00[j]) + w01 * bf2f(a01[j])
                         + w10 * bf2f(a10[j]) + w11 * bf2f(a11[j]);
                float v1 = w00 * bf2f(b00[j]) + w01 * bf2f(b01[j])
                         + w10 * bf2f(b10[j]) + w11 * bf2f(b11[j]);
                bf0[j] = (short)f2bf(v0);
                bf1[j] = (short)f2bf(v1);
            }
        } else {
            int gy = y + ki - PAD;
            int gx = xg + kj - PAD;
            bool ok = (gy >= 0 && gy < HH && gx >= 0 && gx < WID);
            if (ok) {
                const unsigned short* cp = xb + ((size_t)(gy * WID + gx)) * 64 + q8;
                bf0 = *(const short8*)cp;
                bf1 = *(const short8*)(cp + 32);
            } else {
                bf0 = (short8)0; bf1 = (short8)0;
            }
        }

        // ---- MFMA: A=weights (m=o), B=in-register samples (n=pos) ----
        const short8* wp = (const short8*)(wtb + (size_t)k * OP * 64);
#pragma unroll
        for (int ot = 0; ot < NOT; ot++) {
            short8 a0 = wp[(size_t)(ot * 16 + p) * 8 + q];
            acc[ot] = __builtin_amdgcn_mfma_f32_16x16x32_bf16(a0, bf0, acc[ot], 0, 0, 0);
        }
#pragma unroll
        for (int ot = 0; ot < NOT; ot++) {
            short8 a1 = wp[(size_t)(ot * 16 + p) * 8 + 4 + q];
            acc[ot] = __builtin_amdgcn_mfma_f32_16x16x32_bf16(a1, bf1, acc[ot], 0, 0, 0);
        }
    }

    // ---- epilogue: pos = p0 + wave*16 + p; o = ot*16 + q*4 + i ----
    size_t opos = (size_t)p0 + wave * 16 + p;
#pragma unroll
    for (int ot = 0; ot < NOT; ot++) {
        int ob = ot * 16 + q * 4;
        if (DEFORM) {
            unsigned short* outp = (unsigned short*)outv;
            float4 bb = *(const float4*)&bias[ob];
            ushort4v r;
            r[0] = f2bf(acc[ot][0] + bb.x);
            r[1] = f2bf(acc[ot][1] + bb.y);
            r[2] = f2bf(acc[ot][2] + bb.z);
            r[3] = f2bf(acc[ot][3] + bb.w);
            *(ushort4v*)&outp[opos * 64 + ob] = r;
        } else {
            if (ob + 4 <= PITCH) {
                float* outf = (float*)outv;
                float b0 = bias[min(ob + 0, CO - 1)];
                float b1 = bias[min(ob + 1, CO - 1)];
                float b2 = bias[min(ob + 2, CO - 1)];
                float b3 = bias[min(ob + 3, CO - 1)];
                *(float4*)&outf[opos * PITCH + ob] =
                    make_float4(acc[ot][0] + b0, acc[ot][1] + b1,
                                acc[ot][2] + b2, acc[ot][3] + b3);
            }
        }
    }
}

// ---------------------------------------------------------------------------
// K4: h = x1_final + x2 (NHWC bf16); out = h @ w_out^T + b_out + x (NCHW fp32)
// ---------------------------------------------------------------------------
__global__ __launch_bounds__(256) void k_merge_out(
    const unsigned short* __restrict__ x1f, const unsigned short* __restrict__ x2,
    const float* __restrict__ xin, const float* __restrict__ w_out,
    const float* __restrict__ b_out, float* __restrict__ out)
{
    int p  = blockIdx.x * 256 + threadIdx.x;
    int b  = p / HW;
    int hw = p % HW;

    const unsigned short* a1 = x1f + (size_t)p * 64;
    const unsigned short* a2 = x2  + (size_t)p * 64;
    float v[64];
#pragma unroll
    for (int c8 = 0; c8 < 8; c8++) {
        ushort8 u1 = *(const ushort8*)&a1[c8 * 8];
        ushort8 u2 = *(const ushort8*)&a2[c8 * 8];
#pragma unroll
        for (int j = 0; j < 8; j++)
            v[c8 * 8 + j] = bf2f(u1[j]) + bf2f(u2[j]);
    }

    size_t base = (size_t)b * CB * HW + hw;
    for (int o = 0; o < 64; o++) {
        float a = b_out[o] + xin[base + (size_t)o * HW];
#pragma unroll
        for (int c = 0; c < 64; c++) a += v[c] * w_out[o * 64 + c];
        out[base + (size_t)o * HW] = a;
    }
}

// ---------------------------------------------------------------------------
// Launch. Workspace: x1a/x1b/x2 NHWC bf16 (18.9 MB each), off fp32 (59 MB),
// bf16 weight buffers (~1.3 MB). Total ~112 MB.
// ---------------------------------------------------------------------------
extern "C" void kernel_launch(void* const* d_in, const int* in_sizes, int n_in,
                              void* d_out, int out_size, void* d_ws, size_t ws_size,
                              hipStream_t stream)
{
    const float* x     = (const float*)d_in[0];
    const float* ln_w  = (const float*)d_in[1];
    const float* ln_b  = (const float*)d_in[2];
    const float* w_in  = (const float*)d_in[3];
    const float* b_in  = (const float*)d_in[4];
    const float* w_out = (const float*)d_in[5];
    const float* b_out = (const float*)d_in[6];
    const float* dw1   = (const float*)d_in[7];
    const float* db1   = (const float*)d_in[8];
    const float* dw2   = (const float*)d_in[9];
    const float* db2   = (const float*)d_in[10];
    const float* dw3   = (const float*)d_in[11];
    const float* db3   = (const float*)d_in[12];
    const float* ow1   = (const float*)d_in[13];
    const float* ob1   = (const float*)d_in[14];
    const float* ow2   = (const float*)d_in[15];
    const float* ob2   = (const float*)d_in[16];
    const float* ow3   = (const float*)d_in[17];
    const float* ob3   = (const float*)d_in[18];

    unsigned short* x1a = (unsigned short*)d_ws;
    unsigned short* x1b = x1a + (size_t)NPOS * 64;
    unsigned short* x2  = x1b + (size_t)NPOS * 64;
    float* off = (float*)(x2 + (size_t)NPOS * 64);
    unsigned short* wtd1 = (unsigned short*)(off + (size_t)NPOS * 100);
    unsigned short* wtd2 = wtd1 + 49 * 64 * 64;
    unsigned short* wtd3 = wtd2 + 25 * 64 * 64;
    unsigned short* wto1 = wtd3 +  9 * 64 * 64;
    unsigned short* wto2 = wto1 + 25 * 112 * 64;
    unsigned short* wto3 = wto2 + 25 * 64 * 64;

    // weight prep (bf16, [tap][o][c])
    k_wtb<49, 64,  64><<<784, 256, 0, stream>>>(dw1, wtd1);
    k_wtb<25, 64,  64><<<400, 256, 0, stream>>>(dw2, wtd2);
    k_wtb< 9, 64,  64><<<144, 256, 0, stream>>>(dw3, wtd3);
    k_wtb<25, 98, 112><<<700, 256, 0, stream>>>(ow1, wto1);
    k_wtb<25, 50,  64><<<400, 256, 0, stream>>>(ow2, wto2);
    k_wtb< 9, 18,  32><<< 72, 256, 0, stream>>>(ow3, wto3);

    k_ln_conv_in<<<NPOS / 256, 256, 0, stream>>>(x, ln_w, ln_b, w_in, b_in, x1a, x2);

    // stage 1 (off pitch 100)
    k_mconv<5, 2, 7, 98, 100, false><<<NTILE, 256, 0, stream>>>(x1a, off, wto1, ob1, off);
    k_mconv<7, 3, 4, 64, 100, true ><<<NTILE, 256, 0, stream>>>(x1a, off, wtd1, db1, x1b);
    // stage 2 (off pitch 52)
    k_mconv<5, 2, 4, 50,  52, false><<<NTILE, 256, 0, stream>>>(x1b, off, wto2, ob2, off);
    k_mconv<5, 2, 4, 64,  52, true ><<<NTILE, 256, 0, stream>>>(x1b, off, wtd2, db2, x1a);
    // stage 3 (off pitch 20)
    k_mconv<3, 1, 2, 18,  20, false><<<NTILE, 256, 0, stream>>>(x1a, off, wto3, ob3, off);
    k_mconv<3, 1, 4, 64,  20, true ><<<NTILE, 256, 0, stream>>>(x1a, off, wtd3, db3, x1b);

    k_merge_out<<<NPOS / 256, 256, 0, stream>>>(x1b, x2, x, w_out, b_out, (float*)d_out);
}

// Round 6
// 2389.416 us; speedup vs baseline: 10.0120x; 1.0300x over previous
//
#include <hip/hip_runtime.h>

// Problem constants (B=4, C=64, H=W=192)
#define HH 192
#define WID 192
#define HW (HH*WID)          // 36864
#define CB 64
#define BB 4
#define NPOS (BB*HW)         // 147456
#define NTILE (NPOS/64)      // 2304

typedef __attribute__((ext_vector_type(8))) short short8;
typedef __attribute__((ext_vector_type(8))) unsigned short ushort8;
typedef __attribute__((ext_vector_type(4))) unsigned short ushort4v;
typedef __attribute__((ext_vector_type(4))) float f32x4;

static __device__ inline unsigned short f2bf(float f) {
    union { float f; unsigned u; } a; a.f = f;
    return (unsigned short)((a.u + 0x8000u) >> 16);   // round-half-up to bf16
}
static __device__ inline float bf2f(unsigned short h) {
    union { unsigned u; float f; } a; a.u = ((unsigned)h) << 16;
    return a.f;
}

// ---------------------------------------------------------------------------
// K1: LayerNorm over C + 1x1 conv C->2C; outputs x1/x2 in NHWC bf16.
// ---------------------------------------------------------------------------
__global__ __launch_bounds__(256) void k_ln_conv_in(
    const float* __restrict__ x, const float* __restrict__ g, const float* __restrict__ be,
    const float* __restrict__ w_in, const float* __restrict__ b_in,
    unsigned short* __restrict__ x1, unsigned short* __restrict__ x2)
{
    int p  = blockIdx.x * 256 + threadIdx.x;     // [0, NPOS)
    int b  = p / HW;
    int hw = p % HW;
    const float* xp = x + (size_t)b * CB * HW + hw;

    float v[64];
    float sum = 0.f, sumsq = 0.f;
#pragma unroll
    for (int c = 0; c < 64; c++) {
        float t = xp[c * HW];
        v[c] = t; sum += t; sumsq += t * t;
    }
    float mu  = sum * (1.f / 64.f);
    float var = sumsq * (1.f / 64.f) - mu * mu;
    float inv = rsqrtf(var + 1e-5f);
#pragma unroll
    for (int c = 0; c < 64; c++) v[c] = (v[c] - mu) * inv * g[c] + be[c];

    unsigned short* o1 = x1 + (size_t)p * 64;
    unsigned short* o2 = x2 + (size_t)p * 64;
    for (int o8 = 0; o8 < 8; o8++) {
        ushort8 r1, r2;
#pragma unroll
        for (int j = 0; j < 8; j++) {
            int o = o8 * 8 + j;
            float a1 = b_in[o];
            float a2 = b_in[o + 64];
#pragma unroll
            for (int c = 0; c < 64; c++) {
                a1 += v[c] * w_in[o * 64 + c];
                a2 += v[c] * w_in[(o + 64) * 64 + c];
            }
            r1[j] = f2bf(a1);
            r2[j] = f2bf(a2);
        }
        *(ushort8*)&o1[o8 * 8] = r1;
        *(ushort8*)&o2[o8 * 8] = r2;
    }
}

// ---------------------------------------------------------------------------
// Weight prep: w[o][c][ki][kj] fp32 (OIHW) -> wt[k][o][c] bf16, o padded to OP.
// ---------------------------------------------------------------------------
template<int KK, int CO, int OP>
__global__ void k_wtb(const float* __restrict__ w, unsigned short* __restrict__ wt)
{
    int idx = blockIdx.x * 256 + threadIdx.x;
    constexpr int TOT = KK * OP * 64;
    if (idx >= TOT) return;
    int k = idx / (OP * 64);
    int r = idx % (OP * 64);
    int o = r / 64;
    int c = r % 64;
    float v = (o < CO) ? w[((size_t)o * 64 + c) * KK + k] : 0.f;
    wt[idx] = f2bf(v);
}

// ---------------------------------------------------------------------------
// Corner-register set for one in-flight deform tap: 4 corners x 2 K-chunks
// + bilinear weights.
// ---------------------------------------------------------------------------
struct CornerRegs {
    ushort8 r[8];            // {00lo,00hi,01lo,01hi,10lo,10hi,11lo,11hi}
    float w00, w01, w10, w11;
};

static __device__ inline void d_issue(const unsigned short* __restrict__ xb, int q8,
                                      int y, int xg, int ki, int kj, int PAD,
                                      float oy, float ox, CornerRegs& C)
{
    float py = (float)(y + ki - PAD) + oy;
    float px = (float)(xg + kj - PAD) + ox;
    float fy = floorf(py), fx = floorf(px);
    float wy = py - fy, wx = px - fx;
    int iy0 = (int)fy, ix0 = (int)fx;
    int iy1 = iy0 + 1, ix1 = ix0 + 1;
    float m00 = (iy0 >= 0 && iy0 < HH && ix0 >= 0 && ix0 < WID) ? 1.f : 0.f;
    float m01 = (iy0 >= 0 && iy0 < HH && ix1 >= 0 && ix1 < WID) ? 1.f : 0.f;
    float m10 = (iy1 >= 0 && iy1 < HH && ix0 >= 0 && ix0 < WID) ? 1.f : 0.f;
    float m11 = (iy1 >= 0 && iy1 < HH && ix1 >= 0 && ix1 < WID) ? 1.f : 0.f;
    int cy0 = min(max(iy0, 0), HH - 1), cy1 = min(max(iy1, 0), HH - 1);
    int cx0 = min(max(ix0, 0), WID - 1), cx1 = min(max(ix1, 0), WID - 1);
    const unsigned short* c00 = xb + ((size_t)(cy0 * WID + cx0)) * 64 + q8;
    const unsigned short* c01 = xb + ((size_t)(cy0 * WID + cx1)) * 64 + q8;
    const unsigned short* c10 = xb + ((size_t)(cy1 * WID + cx0)) * 64 + q8;
    const unsigned short* c11 = xb + ((size_t)(cy1 * WID + cx1)) * 64 + q8;
    C.r[0] = *(const ushort8*)c00;  C.r[1] = *(const ushort8*)(c00 + 32);
    C.r[2] = *(const ushort8*)c01;  C.r[3] = *(const ushort8*)(c01 + 32);
    C.r[4] = *(const ushort8*)c10;  C.r[5] = *(const ushort8*)(c10 + 32);
    C.r[6] = *(const ushort8*)c11;  C.r[7] = *(const ushort8*)(c11 + 32);
    C.w00 = (1.f - wy) * (1.f - wx) * m00;
    C.w01 = (1.f - wy) * wx * m01;
    C.w10 = wy * (1.f - wx) * m10;
    C.w11 = wy * wx * m11;
}

static __device__ inline void d_combine(const CornerRegs& C, short8& f0, short8& f1)
{
#pragma unroll
    for (int j = 0; j < 8; j++) {
        float v0 = C.w00 * bf2f(C.r[0][j]) + C.w01 * bf2f(C.r[2][j])
                 + C.w10 * bf2f(C.r[4][j]) + C.w11 * bf2f(C.r[6][j]);
        float v1 = C.w00 * bf2f(C.r[1][j]) + C.w01 * bf2f(C.r[3][j])
                 + C.w10 * bf2f(C.r[5][j]) + C.w11 * bf2f(C.r[7][j]);
        f0[j] = (short)f2bf(v0);
        f1[j] = (short)f2bf(v1);
    }
}

static __device__ inline void d_issue_conv(const unsigned short* __restrict__ xb, int q8,
                                           int y, int xg, int ki, int kj, int PAD,
                                           short8& f0, short8& f1)
{
    int gy = y + ki - PAD;
    int gx = xg + kj - PAD;
    bool ok = (gy >= 0 && gy < HH && gx >= 0 && gx < WID);
    if (ok) {
        const unsigned short* cp = xb + ((size_t)(gy * WID + gx)) * 64 + q8;
        f0 = *(const short8*)cp;
        f1 = *(const short8*)(cp + 32);
    } else {
        f0 = (short8)0; f1 = (short8)0;
    }
}

// ---------------------------------------------------------------------------
// Barrier-free wave-local MFMA conv (NHWC bf16 input), software-pipelined:
// tap k+1's corner loads are issued before tap k's bilinear combine + MFMA,
// so the gather latency is hidden behind one tap of compute (no LDS, no syncs).
// Per-tap GEMM: D(o,pos) += W(o,c) * S(c,pos), MFMA 16x16x32 bf16.
// Block = 64 row-aligned positions, 4 waves; wave w owns positions w*16..+15.
// Lane l: p = l&15 (pos/n and o-row/m), q = l>>4 (K-quad).
// DEFORM=true : bilinear sampling via offp (pitch PITCH); out bf16 NHWC pitch 64.
// DEFORM=false: shifted-window sampling; out fp32 NHWC pitch PITCH (offsets).
// ---------------------------------------------------------------------------
template<int K, int PAD, int NOT, int CO, int PITCH, bool DEFORM>
__global__ __launch_bounds__(256) void k_mconv(
    const unsigned short* __restrict__ xin, const float* __restrict__ offp,
    const unsigned short* __restrict__ wtb, const float* __restrict__ bias,
    void* __restrict__ outv)
{
    constexpr int KK = K * K;
    constexpr int OP = NOT * 16;
    static_assert(KK % 2 == 1, "pair-pipelined loop assumes odd tap count");

    int tile = blockIdx.x;
    int p0  = tile * 64;
    int b   = p0 / HW;
    int hw0 = p0 % HW;
    int y   = hw0 / WID;
    int x0  = hw0 % WID;

    int t    = threadIdx.x;
    int lane = t & 63;
    int wave = t >> 6;
    int p    = lane & 15;
    int q    = lane >> 4;
    int q8   = q * 8;
    int xg   = x0 + wave * 16 + p;    // this lane's position (column)
    int wlane = p * 8 + q;            // A-frag lane offset (short8 units)

    f32x4 acc[NOT];
#pragma unroll
    for (int ot = 0; ot < NOT; ot++) acc[ot] = (f32x4){0.f, 0.f, 0.f, 0.f};

    const unsigned short* xb = xin + (size_t)b * HW * 64;               // NHWC image base
    const float* offb = offp + ((size_t)p0 + wave * 16 + p) * PITCH;    // lane's offsets
    const short8* wbase = (const short8*)wtb;

    // consume one tap: hoist A-frag loads, combine/own frags, MFMA
    auto consume = [&](short8 f0, short8 f1, int k) {
        const short8* wp = wbase + (size_t)k * OP * 8;
        short8 aw0[NOT], aw1[NOT];
#pragma unroll
        for (int ot = 0; ot < NOT; ot++) {
            aw0[ot] = wp[ot * 128 + wlane];
            aw1[ot] = wp[ot * 128 + wlane + 4];
        }
#pragma unroll
        for (int ot = 0; ot < NOT; ot++)
            acc[ot] = __builtin_amdgcn_mfma_f32_16x16x32_bf16(aw0[ot], f0, acc[ot], 0, 0, 0);
#pragma unroll
        for (int ot = 0; ot < NOT; ot++)
            acc[ot] = __builtin_amdgcn_mfma_f32_16x16x32_bf16(aw1[ot], f1, acc[ot], 0, 0, 0);
    };

    if (DEFORM) {
        auto consumeC = [&](const CornerRegs& C, int k) {
            const short8* wp = wbase + (size_t)k * OP * 8;
            short8 aw0[NOT], aw1[NOT];
#pragma unroll
            for (int ot = 0; ot < NOT; ot++) {
                aw0[ot] = wp[ot * 128 + wlane];
                aw1[ot] = wp[ot * 128 + wlane + 4];
            }
            short8 f0, f1;
            d_combine(C, f0, f1);
#pragma unroll
            for (int ot = 0; ot < NOT; ot++)
                acc[ot] = __builtin_amdgcn_mfma_f32_16x16x32_bf16(aw0[ot], f0, acc[ot], 0, 0, 0);
#pragma unroll
            for (int ot = 0; ot < NOT; ot++)
                acc[ot] = __builtin_amdgcn_mfma_f32_16x16x32_bf16(aw1[ot], f1, acc[ot], 0, 0, 0);
        };

        CornerRegs C0, C1;
        float2 off0 = *(const float2*)&offb[0];
        float2 offA = *(const float2*)&offb[2];           // offsets for tap 1
        float2 offB;
        d_issue(xb, q8, y, xg, 0, 0, PAD, off0.x, off0.y, C0);

        for (int k = 0; k < KK - 1; k += 2) {
            offB = *(const float2*)&offb[2 * (k + 2)];    // for tap k+2 (in-bounds: pitch = 2KK+2)
            {
                int kn = k + 1;
                d_issue(xb, q8, y, xg, kn / K, kn % K, PAD, offA.x, offA.y, C1);
            }
            consumeC(C0, k);
            offA = *(const float2*)&offb[2 * (k + 3)];    // may read pad floats; used only if valid
            {
                int kn = k + 2;
                d_issue(xb, q8, y, xg, kn / K, kn % K, PAD, offB.x, offB.y, C0);
            }
            consumeC(C1, k + 1);
        }
        consumeC(C0, KK - 1);
    } else {
        short8 f0a, f1a, f0b, f1b;
        d_issue_conv(xb, q8, y, xg, 0, 0, PAD, f0a, f1a);
        for (int k = 0; k < KK - 1; k += 2) {
            {
                int kn = k + 1;
                d_issue_conv(xb, q8, y, xg, kn / K, kn % K, PAD, f0b, f1b);
            }
            consume(f0a, f1a, k);
            {
                int kn = k + 2;
                d_issue_conv(xb, q8, y, xg, kn / K, kn % K, PAD, f0a, f1a);
            }
            consume(f0b, f1b, k + 1);
        }
        consume(f0a, f1a, KK - 1);
    }

    // ---- epilogue: pos = p0 + wave*16 + p; o = ot*16 + q*4 + i ----
    size_t opos = (size_t)p0 + wave * 16 + p;
#pragma unroll
    for (int ot = 0; ot < NOT; ot++) {
        int ob = ot * 16 + q * 4;
        if (DEFORM) {
            unsigned short* outp = (unsigned short*)outv;
            float4 bb = *(const float4*)&bias[ob];
            ushort4v r;
            r[0] = f2bf(acc[ot][0] + bb.x);
            r[1] = f2bf(acc[ot][1] + bb.y);
            r[2] = f2bf(acc[ot][2] + bb.z);
            r[3] = f2bf(acc[ot][3] + bb.w);
            *(ushort4v*)&outp[opos * 64 + ob] = r;
        } else {
            if (ob + 4 <= PITCH) {
                float* outf = (float*)outv;
                float b0 = bias[min(ob + 0, CO - 1)];
                float b1 = bias[min(ob + 1, CO - 1)];
                float b2 = bias[min(ob + 2, CO - 1)];
                float b3 = bias[min(ob + 3, CO - 1)];
                *(float4*)&outf[opos * PITCH + ob] =
                    make_float4(acc[ot][0] + b0, acc[ot][1] + b1,
                                acc[ot][2] + b2, acc[ot][3] + b3);
            }
        }
    }
}

// ---------------------------------------------------------------------------
// K4: h = x1_final + x2 (NHWC bf16); out = h @ w_out^T + b_out + x (NCHW fp32)
// ---------------------------------------------------------------------------
__global__ __launch_bounds__(256) void k_merge_out(
    const unsigned short* __restrict__ x1f, const unsigned short* __restrict__ x2,
    const float* __restrict__ xin, const float* __restrict__ w_out,
    const float* __restrict__ b_out, float* __restrict__ out)
{
    int p  = blockIdx.x * 256 + threadIdx.x;
    int b  = p / HW;
    int hw = p % HW;

    const unsigned short* a1 = x1f + (size_t)p * 64;
    const unsigned short* a2 = x2  + (size_t)p * 64;
    float v[64];
#pragma unroll
    for (int c8 = 0; c8 < 8; c8++) {
        ushort8 u1 = *(const ushort8*)&a1[c8 * 8];
        ushort8 u2 = *(const ushort8*)&a2[c8 * 8];
#pragma unroll
        for (int j = 0; j < 8; j++)
            v[c8 * 8 + j] = bf2f(u1[j]) + bf2f(u2[j]);
    }

    size_t base = (size_t)b * CB * HW + hw;
    for (int o = 0; o < 64; o++) {
        float a = b_out[o] + xin[base + (size_t)o * HW];
#pragma unroll
        for (int c = 0; c < 64; c++) a += v[c] * w_out[o * 64 + c];
        out[base + (size_t)o * HW] = a;
    }
}

// ---------------------------------------------------------------------------
// Launch. Workspace: x1a/x1b/x2 NHWC bf16 (18.9 MB each), off fp32 (59 MB),
// bf16 weight buffers (~1.3 MB). Total ~112 MB.
// ---------------------------------------------------------------------------
extern "C" void kernel_launch(void* const* d_in, const int* in_sizes, int n_in,
                              void* d_out, int out_size, void* d_ws, size_t ws_size,
                              hipStream_t stream)
{
    const float* x     = (const float*)d_in[0];
    const float* ln_w  = (const float*)d_in[1];
    const float* ln_b  = (const float*)d_in[2];
    const float* w_in  = (const float*)d_in[3];
    const float* b_in  = (const float*)d_in[4];
    const float* w_out = (const float*)d_in[5];
    const float* b_out = (const float*)d_in[6];
    const float* dw1   = (const float*)d_in[7];
    const float* db1   = (const float*)d_in[8];
    const float* dw2   = (const float*)d_in[9];
    const float* db2   = (const float*)d_in[10];
    const float* dw3   = (const float*)d_in[11];
    const float* db3   = (const float*)d_in[12];
    const float* ow1   = (const float*)d_in[13];
    const float* ob1   = (const float*)d_in[14];
    const float* ow2   = (const float*)d_in[15];
    const float* ob2   = (const float*)d_in[16];
    const float* ow3   = (const float*)d_in[17];
    const float* ob3   = (const float*)d_in[18];

    unsigned short* x1a = (unsigned short*)d_ws;
    unsigned short* x1b = x1a + (size_t)NPOS * 64;
    unsigned short* x2  = x1b + (size_t)NPOS * 64;
    float* off = (float*)(x2 + (size_t)NPOS * 64);
    unsigned short* wtd1 = (unsigned short*)(off + (size_t)NPOS * 100);
    unsigned short* wtd2 = wtd1 + 49 * 64 * 64;
    unsigned short* wtd3 = wtd2 + 25 * 64 * 64;
    unsigned short* wto1 = wtd3 +  9 * 64 * 64;
    unsigned short* wto2 = wto1 + 25 * 112 * 64;
    unsigned short* wto3 = wto2 + 25 * 64 * 64;

    // weight prep (bf16, [tap][o][c])
    k_wtb<49, 64,  64><<<784, 256, 0, stream>>>(dw1, wtd1);
    k_wtb<25, 64,  64><<<400, 256, 0, stream>>>(dw2, wtd2);
    k_wtb< 9, 64,  64><<<144, 256, 0, stream>>>(dw3, wtd3);
    k_wtb<25, 98, 112><<<700, 256, 0, stream>>>(ow1, wto1);
    k_wtb<25, 50,  64><<<400, 256, 0, stream>>>(ow2, wto2);
    k_wtb< 9, 18,  32><<< 72, 256, 0, stream>>>(ow3, wto3);

    k_ln_conv_in<<<NPOS / 256, 256, 0, stream>>>(x, ln_w, ln_b, w_in, b_in, x1a, x2);

    // stage 1 (off pitch 100)
    k_mconv<5, 2, 7, 98, 100, false><<<NTILE, 256, 0, stream>>>(x1a, off, wto1, ob1, off);
    k_mconv<7, 3, 4, 64, 100, true ><<<NTILE, 256, 0, stream>>>(x1a, off, wtd1, db1, x1b);
    // stage 2 (off pitch 52)
    k_mconv<5, 2, 4, 50,  52, false><<<NTILE, 256, 0, stream>>>(x1b, off, wto2, ob2, off);
    k_mconv<5, 2, 4, 64,  52, true ><<<NTILE, 256, 0, stream>>>(x1b, off, wtd2, db2, x1a);
    // stage 3 (off pitch 20)
    k_mconv<3, 1, 2, 18,  20, false><<<NTILE, 256, 0, stream>>>(x1a, off, wto3, ob3, off);
    k_mconv<3, 1, 4, 64,  20, true ><<<NTILE, 256, 0, stream>>>(x1a, off, wtd3, db3, x1b);

    k_merge_out<<<NPOS / 256, 256, 0, stream>>>(x1b, x2, x, w_out, b_out, (float*)d_out);
}

// Round 7
// 1868.590 us; speedup vs baseline: 12.8026x; 1.2787x over previous
//
#include <hip/hip_runtime.h>

// Problem constants (B=4, C=64, H=W=192)
#define HH 192
#define WID 192
#define HW (HH*WID)          // 36864
#define CB 64
#define BB 4
#define NPOS (BB*HW)         // 147456
#define NTILE (NPOS/64)      // 2304

typedef __attribute__((ext_vector_type(8))) short short8;
typedef __attribute__((ext_vector_type(8))) unsigned short ushort8;
typedef __attribute__((ext_vector_type(4))) unsigned short ushort4v;
typedef __attribute__((ext_vector_type(4))) float f32x4;

static __device__ inline unsigned short f2bf(float f) {
    union { float f; unsigned u; } a; a.f = f;
    return (unsigned short)((a.u + 0x8000u) >> 16);   // round-half-up to bf16
}
static __device__ inline float bf2f(unsigned short h) {
    union { unsigned u; float f; } a; a.u = ((unsigned)h) << 16;
    return a.f;
}

// x tensors live in CHANNEL-PLANE layout: x[b][plane=c>>3][hw][8ch] (16B/pos/plane).
// Offsets live in TAP-MAJOR layout: off[k][global_pos][2] (float2 planes, NPOS each).

// ---------------------------------------------------------------------------
// K1: LayerNorm over C + 1x1 conv C->2C; outputs x1/x2 in plane-bf16 layout.
// ---------------------------------------------------------------------------
__global__ __launch_bounds__(256) void k_ln_conv_in(
    const float* __restrict__ x, const float* __restrict__ g, const float* __restrict__ be,
    const float* __restrict__ w_in, const float* __restrict__ b_in,
    unsigned short* __restrict__ x1, unsigned short* __restrict__ x2)
{
    int p  = blockIdx.x * 256 + threadIdx.x;     // [0, NPOS)
    int b  = p / HW;
    int hw = p % HW;
    const float* xp = x + (size_t)b * CB * HW + hw;

    float v[64];
    float sum = 0.f, sumsq = 0.f;
#pragma unroll
    for (int c = 0; c < 64; c++) {
        float t = xp[c * HW];
        v[c] = t; sum += t; sumsq += t * t;
    }
    float mu  = sum * (1.f / 64.f);
    float var = sumsq * (1.f / 64.f) - mu * mu;
    float inv = rsqrtf(var + 1e-5f);
#pragma unroll
    for (int c = 0; c < 64; c++) v[c] = (v[c] - mu) * inv * g[c] + be[c];

    unsigned short* o1 = x1 + (size_t)b * HW * 64 + (size_t)hw * 8;
    unsigned short* o2 = x2 + (size_t)b * HW * 64 + (size_t)hw * 8;
    for (int pl = 0; pl < 8; pl++) {            // pl = channel plane (8 ch)
        ushort8 r1, r2;
#pragma unroll
        for (int j = 0; j < 8; j++) {
            int o = pl * 8 + j;
            float a1 = b_in[o];
            float a2 = b_in[o + 64];
#pragma unroll
            for (int c = 0; c < 64; c++) {
                a1 += v[c] * w_in[o * 64 + c];
                a2 += v[c] * w_in[(o + 64) * 64 + c];
            }
            r1[j] = f2bf(a1);
            r2[j] = f2bf(a2);
        }
        *(ushort8*)&o1[(size_t)pl * HW * 8] = r1;
        *(ushort8*)&o2[(size_t)pl * HW * 8] = r2;
    }
}

// ---------------------------------------------------------------------------
// Weight prep: w[o][c][ki][kj] fp32 (OIHW) -> wt[k][o][c] bf16, o padded to OP.
// ---------------------------------------------------------------------------
template<int KK, int CO, int OP>
__global__ void k_wtb(const float* __restrict__ w, unsigned short* __restrict__ wt)
{
    int idx = blockIdx.x * 256 + threadIdx.x;
    constexpr int TOT = KK * OP * 64;
    if (idx >= TOT) return;
    int k = idx / (OP * 64);
    int r = idx % (OP * 64);
    int o = r / 64;
    int c = r % 64;
    float v = (o < CO) ? w[((size_t)o * 64 + c) * KK + k] : 0.f;
    wt[idx] = f2bf(v);
}

// ---------------------------------------------------------------------------
// Corner-register set for one in-flight deform tap.
// ---------------------------------------------------------------------------
struct CornerRegs {
    ushort8 r[8];            // {00lo,00hi,01lo,01hi,10lo,10hi,11lo,11hi}
    float w00, w01, w10, w11;
};

static __device__ inline void d_issue(const unsigned short* __restrict__ xq0,
                                      const unsigned short* __restrict__ xq1,
                                      int y, int xg, int ki, int kj, int PAD,
                                      float oy, float ox, CornerRegs& C)
{
    float py = (float)(y + ki - PAD) + oy;
    float px = (float)(xg + kj - PAD) + ox;
    float fy = floorf(py), fx = floorf(px);
    float wy = py - fy, wx = px - fx;
    int iy0 = (int)fy, ix0 = (int)fx;
    int iy1 = iy0 + 1, ix1 = ix0 + 1;
    float m00 = (iy0 >= 0 && iy0 < HH && ix0 >= 0 && ix0 < WID) ? 1.f : 0.f;
    float m01 = (iy0 >= 0 && iy0 < HH && ix1 >= 0 && ix1 < WID) ? 1.f : 0.f;
    float m10 = (iy1 >= 0 && iy1 < HH && ix0 >= 0 && ix0 < WID) ? 1.f : 0.f;
    float m11 = (iy1 >= 0 && iy1 < HH && ix1 >= 0 && ix1 < WID) ? 1.f : 0.f;
    int cy0 = min(max(iy0, 0), HH - 1), cy1 = min(max(iy1, 0), HH - 1);
    int cx0 = min(max(ix0, 0), WID - 1), cx1 = min(max(ix1, 0), WID - 1);
    size_t i00 = (size_t)(cy0 * WID + cx0) * 8, i01 = (size_t)(cy0 * WID + cx1) * 8;
    size_t i10 = (size_t)(cy1 * WID + cx0) * 8, i11 = (size_t)(cy1 * WID + cx1) * 8;
    C.r[0] = *(const ushort8*)(xq0 + i00);  C.r[1] = *(const ushort8*)(xq1 + i00);
    C.r[2] = *(const ushort8*)(xq0 + i01);  C.r[3] = *(const ushort8*)(xq1 + i01);
    C.r[4] = *(const ushort8*)(xq0 + i10);  C.r[5] = *(const ushort8*)(xq1 + i10);
    C.r[6] = *(const ushort8*)(xq0 + i11);  C.r[7] = *(const ushort8*)(xq1 + i11);
    C.w00 = (1.f - wy) * (1.f - wx) * m00;
    C.w01 = (1.f - wy) * wx * m01;
    C.w10 = wy * (1.f - wx) * m10;
    C.w11 = wy * wx * m11;
}

static __device__ inline void d_combine(const CornerRegs& C, short8& f0, short8& f1)
{
#pragma unroll
    for (int j = 0; j < 8; j++) {
        float v0 = C.w00 * bf2f(C.r[0][j]) + C.w01 * bf2f(C.r[2][j])
                 + C.w10 * bf2f(C.r[4][j]) + C.w11 * bf2f(C.r[6][j]);
        float v1 = C.w00 * bf2f(C.r[1][j]) + C.w01 * bf2f(C.r[3][j])
                 + C.w10 * bf2f(C.r[5][j]) + C.w11 * bf2f(C.r[7][j]);
        f0[j] = (short)f2bf(v0);
        f1[j] = (short)f2bf(v1);
    }
}

static __device__ inline void d_issue_conv(const unsigned short* __restrict__ xq0,
                                           const unsigned short* __restrict__ xq1,
                                           int y, int xg, int ki, int kj, int PAD,
                                           short8& f0, short8& f1)
{
    int gy = y + ki - PAD;
    int gx = xg + kj - PAD;
    bool ok = (gy >= 0 && gy < HH && gx >= 0 && gx < WID);
    if (ok) {
        size_t i = (size_t)(gy * WID + gx) * 8;
        f0 = *(const short8*)(xq0 + i);
        f1 = *(const short8*)(xq1 + i);
    } else {
        f0 = (short8)0; f1 = (short8)0;
    }
}

// ---------------------------------------------------------------------------
// Barrier-free wave-local MFMA conv, plane layout, software-pipelined.
// Per-tap GEMM: D(o,pos) += W(o,c) * S(c,pos), MFMA 16x16x32 bf16.
// Block = 64 row-aligned positions, 4 waves; wave w owns positions w*16..+15.
// Lane l: p = l&15 (pos/n and o-row/m), q = l>>4 (K-quad).
// Chunk-0 B-frag channels = plane q; chunk-1 = plane q+4 -> all sample loads
// are lane-consecutive 16B (TA-coalesced). Offsets read from tap-major planes.
// DEFORM=true : bilinear sampling; out = plane-bf16 x tensor.
// DEFORM=false: shifted window;   out = tap-major float2 offset planes.
// ---------------------------------------------------------------------------
template<int K, int PAD, int NOT, int CO, bool DEFORM>
__global__ __launch_bounds__(256) void k_mconv(
    const unsigned short* __restrict__ xin, const float* __restrict__ offp,
    const unsigned short* __restrict__ wtb, const float* __restrict__ bias,
    void* __restrict__ outv)
{
    constexpr int KK = K * K;
    constexpr int OP = NOT * 16;
    constexpr int KTAP = CO / 2;                 // tap count of the offset consumer
    static_assert(KK % 2 == 1, "pair-pipelined loop assumes odd tap count");

    int tile = blockIdx.x;
    int p0  = tile * 64;
    int b   = p0 / HW;
    int hw0 = p0 % HW;
    int y   = hw0 / WID;
    int x0  = hw0 % WID;

    int t    = threadIdx.x;
    int lane = t & 63;
    int wave = t >> 6;
    int p    = lane & 15;
    int q    = lane >> 4;
    int xg   = x0 + wave * 16 + p;    // this lane's position (column)
    int gp   = p0 + wave * 16 + p;    // global position
    int wlane = p * 8 + q;            // A-frag lane offset (short8 units)

    f32x4 acc[NOT];
#pragma unroll
    for (int ot = 0; ot < NOT; ot++) acc[ot] = (f32x4){0.f, 0.f, 0.f, 0.f};

    const unsigned short* xb  = xin + (size_t)b * HW * 64;        // image base
    const unsigned short* xq0 = xb + (size_t)q * HW * 8;          // chunk-0 plane
    const unsigned short* xq1 = xb + (size_t)(q + 4) * HW * 8;    // chunk-1 plane
    const short8* wbase = (const short8*)wtb;

    auto consume = [&](short8 f0, short8 f1, int k) {
        const short8* wp = wbase + (size_t)k * OP * 8;
        short8 aw0[NOT], aw1[NOT];
#pragma unroll
        for (int ot = 0; ot < NOT; ot++) {
            aw0[ot] = wp[ot * 128 + wlane];
            aw1[ot] = wp[ot * 128 + wlane + 4];
        }
#pragma unroll
        for (int ot = 0; ot < NOT; ot++)
            acc[ot] = __builtin_amdgcn_mfma_f32_16x16x32_bf16(aw0[ot], f0, acc[ot], 0, 0, 0);
#pragma unroll
        for (int ot = 0; ot < NOT; ot++)
            acc[ot] = __builtin_amdgcn_mfma_f32_16x16x32_bf16(aw1[ot], f1, acc[ot], 0, 0, 0);
    };

    if (DEFORM) {
        auto consumeC = [&](const CornerRegs& C, int k) {
            const short8* wp = wbase + (size_t)k * OP * 8;
            short8 aw0[NOT], aw1[NOT];
#pragma unroll
            for (int ot = 0; ot < NOT; ot++) {
                aw0[ot] = wp[ot * 128 + wlane];
                aw1[ot] = wp[ot * 128 + wlane + 4];
            }
            short8 f0, f1;
            d_combine(C, f0, f1);
#pragma unroll
            for (int ot = 0; ot < NOT; ot++)
                acc[ot] = __builtin_amdgcn_mfma_f32_16x16x32_bf16(aw0[ot], f0, acc[ot], 0, 0, 0);
#pragma unroll
            for (int ot = 0; ot < NOT; ot++)
                acc[ot] = __builtin_amdgcn_mfma_f32_16x16x32_bf16(aw1[ot], f1, acc[ot], 0, 0, 0);
        };

        const float2* offptr = (const float2*)offp + gp;   // tap-major planes
        CornerRegs C0, C1;
        float2 off0 = offptr[0];
        float2 offA = offptr[NPOS];
        float2 offB;
        d_issue(xq0, xq1, y, xg, 0, 0, PAD, off0.x, off0.y, C0);

        for (int k = 0; k < KK - 1; k += 2) {
            offB = offptr[(size_t)(k + 2) * NPOS];
            {
                int kn = k + 1;
                d_issue(xq0, xq1, y, xg, kn / K, kn % K, PAD, offA.x, offA.y, C1);
            }
            consumeC(C0, k);
            offA = offptr[(size_t)(k + 3) * NPOS];   // last iter reads 1 plane past KK-1; buffer padded
            {
                int kn = k + 2;
                d_issue(xq0, xq1, y, xg, kn / K, kn % K, PAD, offB.x, offB.y, C0);
            }
            consumeC(C1, k + 1);
        }
        consumeC(C0, KK - 1);
    } else {
        short8 f0a, f1a, f0b, f1b;
        d_issue_conv(xq0, xq1, y, xg, 0, 0, PAD, f0a, f1a);
        for (int k = 0; k < KK - 1; k += 2) {
            {
                int kn = k + 1;
                d_issue_conv(xq0, xq1, y, xg, kn / K, kn % K, PAD, f0b, f1b);
            }
            consume(f0a, f1a, k);
            {
                int kn = k + 2;
                d_issue_conv(xq0, xq1, y, xg, kn / K, kn % K, PAD, f0a, f1a);
            }
            consume(f0b, f1b, k + 1);
        }
        consume(f0a, f1a, KK - 1);
    }

    // ---- epilogue: D reg i -> o = ot*16 + q*4 + i, pos = gp ----
    if (DEFORM) {
        unsigned short* outp = (unsigned short*)outv;
        int hw = hw0 + wave * 16 + p;
#pragma unroll
        for (int ot = 0; ot < NOT; ot++) {
            int ob = ot * 16 + q * 4;
            int plane = ob >> 3;
            int intra = ob & 7;
            float4 bb = *(const float4*)&bias[ob];
            ushort4v r;
            r[0] = f2bf(acc[ot][0] + bb.x);
            r[1] = f2bf(acc[ot][1] + bb.y);
            r[2] = f2bf(acc[ot][2] + bb.z);
            r[3] = f2bf(acc[ot][3] + bb.w);
            *(ushort4v*)&outp[(size_t)b * HW * 64 + (size_t)plane * HW * 8
                              + (size_t)hw * 8 + intra] = r;
        }
    } else {
        float* outf = (float*)outv;   // tap-major float2 planes
#pragma unroll
        for (int ot = 0; ot < NOT; ot++) {
            int ob = ot * 16 + q * 4;     // channels ob..ob+3 = taps ob/2, ob/2+1
            int t0 = ob >> 1;
            if (t0 < KTAP) {
                float2 r; r.x = acc[ot][0] + bias[ob];     r.y = acc[ot][1] + bias[ob + 1];
                *(float2*)&outf[((size_t)t0 * NPOS + gp) * 2] = r;
            }
            if (t0 + 1 < KTAP) {
                float2 r; r.x = acc[ot][2] + bias[ob + 2]; r.y = acc[ot][3] + bias[ob + 3];
                *(float2*)&outf[((size_t)(t0 + 1) * NPOS + gp) * 2] = r;
            }
        }
    }
}

// ---------------------------------------------------------------------------
// K4: h = x1_final + x2 (plane bf16); out = h @ w_out^T + b_out + x (NCHW fp32)
// ---------------------------------------------------------------------------
__global__ __launch_bounds__(256) void k_merge_out(
    const unsigned short* __restrict__ x1f, const unsigned short* __restrict__ x2,
    const float* __restrict__ xin, const float* __restrict__ w_out,
    const float* __restrict__ b_out, float* __restrict__ out)
{
    int p  = blockIdx.x * 256 + threadIdx.x;
    int b  = p / HW;
    int hw = p % HW;

    const unsigned short* a1 = x1f + (size_t)b * HW * 64 + (size_t)hw * 8;
    const unsigned short* a2 = x2  + (size_t)b * HW * 64 + (size_t)hw * 8;
    float v[64];
#pragma unroll
    for (int pl = 0; pl < 8; pl++) {
        ushort8 u1 = *(const ushort8*)&a1[(size_t)pl * HW * 8];
        ushort8 u2 = *(const ushort8*)&a2[(size_t)pl * HW * 8];
#pragma unroll
        for (int j = 0; j < 8; j++)
            v[pl * 8 + j] = bf2f(u1[j]) + bf2f(u2[j]);
    }

    size_t base = (size_t)b * CB * HW + hw;
    for (int o = 0; o < 64; o++) {
        float a = b_out[o] + xin[base + (size_t)o * HW];
#pragma unroll
        for (int c = 0; c < 64; c++) a += v[c] * w_out[o * 64 + c];
        out[base + (size_t)o * HW] = a;
    }
}

// ---------------------------------------------------------------------------
// Launch. Workspace: x1a/x1b/x2 plane bf16 (18.9 MB each), off tap-major
// float2 planes (<=50 planes * NPOS = 59 MB), bf16 weights (~1.3 MB).
// ---------------------------------------------------------------------------
extern "C" void kernel_launch(void* const* d_in, const int* in_sizes, int n_in,
                              void* d_out, int out_size, void* d_ws, size_t ws_size,
                              hipStream_t stream)
{
    const float* x     = (const float*)d_in[0];
    const float* ln_w  = (const float*)d_in[1];
    const float* ln_b  = (const float*)d_in[2];
    const float* w_in  = (const float*)d_in[3];
    const float* b_in  = (const float*)d_in[4];
    const float* w_out = (const float*)d_in[5];
    const float* b_out = (const float*)d_in[6];
    const float* dw1   = (const float*)d_in[7];
    const float* db1   = (const float*)d_in[8];
    const float* dw2   = (const float*)d_in[9];
    const float* db2   = (const float*)d_in[10];
    const float* dw3   = (const float*)d_in[11];
    const float* db3   = (const float*)d_in[12];
    const float* ow1   = (const float*)d_in[13];
    const float* ob1   = (const float*)d_in[14];
    const float* ow2   = (const float*)d_in[15];
    const float* ob2   = (const float*)d_in[16];
    const float* ow3   = (const float*)d_in[17];
    const float* ob3   = (const float*)d_in[18];

    unsigned short* x1a = (unsigned short*)d_ws;
    unsigned short* x1b = x1a + (size_t)NPOS * 64;
    unsigned short* x2  = x1b + (size_t)NPOS * 64;
    float* off = (float*)(x2 + (size_t)NPOS * 64);
    unsigned short* wtd1 = (unsigned short*)(off + (size_t)NPOS * 100);
    unsigned short* wtd2 = wtd1 + 49 * 64 * 64;
    unsigned short* wtd3 = wtd2 + 25 * 64 * 64;
    unsigned short* wto1 = wtd3 +  9 * 64 * 64;
    unsigned short* wto2 = wto1 + 25 * 112 * 64;
    unsigned short* wto3 = wto2 + 25 * 64 * 64;

    // weight prep (bf16, [tap][o][c])
    k_wtb<49, 64,  64><<<784, 256, 0, stream>>>(dw1, wtd1);
    k_wtb<25, 64,  64><<<400, 256, 0, stream>>>(dw2, wtd2);
    k_wtb< 9, 64,  64><<<144, 256, 0, stream>>>(dw3, wtd3);
    k_wtb<25, 98, 112><<<700, 256, 0, stream>>>(ow1, wto1);
    k_wtb<25, 50,  64><<<400, 256, 0, stream>>>(ow2, wto2);
    k_wtb< 9, 18,  32><<< 72, 256, 0, stream>>>(ow3, wto3);

    k_ln_conv_in<<<NPOS / 256, 256, 0, stream>>>(x, ln_w, ln_b, w_in, b_in, x1a, x2);

    // stage 1
    k_mconv<5, 2, 7, 98, false><<<NTILE, 256, 0, stream>>>(x1a, off, wto1, ob1, off);
    k_mconv<7, 3, 4, 64, true ><<<NTILE, 256, 0, stream>>>(x1a, off, wtd1, db1, x1b);
    // stage 2
    k_mconv<5, 2, 4, 50, false><<<NTILE, 256, 0, stream>>>(x1b, off, wto2, ob2, off);
    k_mconv<5, 2, 4, 64, true ><<<NTILE, 256, 0, stream>>>(x1b, off, wtd2, db2, x1a);
    // stage 3
    k_mconv<3, 1, 2, 18, false><<<NTILE, 256, 0, stream>>>(x1a, off, wto3, ob3, off);
    k_mconv<3, 1, 4, 64, true ><<<NTILE, 256, 0, stream>>>(x1a, off, wtd3, db3, x1b);

    k_merge_out<<<NPOS / 256, 256, 0, stream>>>(x1b, x2, x, w_out, b_out, (float*)d_out);
}

// Round 8
// 1618.652 us; speedup vs baseline: 14.7794x; 1.1544x over previous
//
#include <hip/hip_runtime.h>

// Problem constants (B=4, C=64, H=W=192)
#define HH 192
#define WID 192
#define HW (HH*WID)          // 36864
#define CB 64
#define BB 4
#define NPOS (BB*HW)         // 147456

typedef __attribute__((ext_vector_type(8))) _Float16 half8v;
typedef __attribute__((ext_vector_type(4))) _Float16 half4v;
typedef __attribute__((ext_vector_type(8))) unsigned short ushort8;
typedef __attribute__((ext_vector_type(4))) float f32x4;

static __device__ inline half8v splat8(_Float16 x) {
    half8v v = {x, x, x, x, x, x, x, x};
    return v;
}

// x tensors: CHANNEL-PLANE fp16 layout x[b][plane=c>>3][hw][8ch] (16B/pos/plane).
// Offsets: TAP-MAJOR float2 planes off[k][global_pos][2] (NPOS float2 per plane).

// ---------------------------------------------------------------------------
// K1: LayerNorm over C + 1x1 conv C->2C; outputs x1/x2 in plane-fp16 layout.
// ---------------------------------------------------------------------------
__global__ __launch_bounds__(256) void k_ln_conv_in(
    const float* __restrict__ x, const float* __restrict__ g, const float* __restrict__ be,
    const float* __restrict__ w_in, const float* __restrict__ b_in,
    _Float16* __restrict__ x1, _Float16* __restrict__ x2)
{
    int p  = blockIdx.x * 256 + threadIdx.x;     // [0, NPOS)
    int b  = p / HW;
    int hw = p % HW;
    const float* xp = x + (size_t)b * CB * HW + hw;

    float v[64];
    float sum = 0.f, sumsq = 0.f;
#pragma unroll
    for (int c = 0; c < 64; c++) {
        float t = xp[c * HW];
        v[c] = t; sum += t; sumsq += t * t;
    }
    float mu  = sum * (1.f / 64.f);
    float var = sumsq * (1.f / 64.f) - mu * mu;
    float inv = rsqrtf(var + 1e-5f);
#pragma unroll
    for (int c = 0; c < 64; c++) v[c] = (v[c] - mu) * inv * g[c] + be[c];

    _Float16* o1 = x1 + (size_t)b * HW * 64 + (size_t)hw * 8;
    _Float16* o2 = x2 + (size_t)b * HW * 64 + (size_t)hw * 8;
    for (int pl = 0; pl < 8; pl++) {            // pl = channel plane (8 ch)
        half8v r1, r2;
#pragma unroll
        for (int j = 0; j < 8; j++) {
            int o = pl * 8 + j;
            float a1 = b_in[o];
            float a2 = b_in[o + 64];
#pragma unroll
            for (int c = 0; c < 64; c++) {
                a1 += v[c] * w_in[o * 64 + c];
                a2 += v[c] * w_in[(o + 64) * 64 + c];
            }
            r1[j] = (_Float16)a1;
            r2[j] = (_Float16)a2;
        }
        *(half8v*)&o1[(size_t)pl * HW * 8] = r1;
        *(half8v*)&o2[(size_t)pl * HW * 8] = r2;
    }
}

// ---------------------------------------------------------------------------
// Weight prep: w[o][c][ki][kj] fp32 (OIHW) -> wt[k][o][c] fp16, o padded to OP.
// ---------------------------------------------------------------------------
template<int KK, int CO, int OP>
__global__ void k_wth(const float* __restrict__ w, _Float16* __restrict__ wt)
{
    int idx = blockIdx.x * 256 + threadIdx.x;
    constexpr int TOT = KK * OP * 64;
    if (idx >= TOT) return;
    int k = idx / (OP * 64);
    int r = idx % (OP * 64);
    int o = r / 64;
    int c = r % 64;
    float v = (o < CO) ? w[((size_t)o * 64 + c) * KK + k] : 0.f;
    wt[idx] = (_Float16)v;
}

// ---------------------------------------------------------------------------
// Corner-register set for one in-flight deform tile-tap.
// ---------------------------------------------------------------------------
struct CornerRegs {
    half8v r[8];             // {00lo,00hi,01lo,01hi,10lo,10hi,11lo,11hi}
    float w00, w01, w10, w11;
};

static __device__ inline void d_issue(const _Float16* __restrict__ xq0,
                                      const _Float16* __restrict__ xq1,
                                      int y, int xg, int ki, int kj, int PAD,
                                      float2 off, CornerRegs& C)
{
    float py = (float)(y + ki - PAD) + off.x;
    float px = (float)(xg + kj - PAD) + off.y;
    float fy = floorf(py), fx = floorf(px);
    float wy = py - fy, wx = px - fx;
    int iy0 = (int)fy, ix0 = (int)fx;
    int iy1 = iy0 + 1, ix1 = ix0 + 1;
    float m00 = (iy0 >= 0 && iy0 < HH && ix0 >= 0 && ix0 < WID) ? 1.f : 0.f;
    float m01 = (iy0 >= 0 && iy0 < HH && ix1 >= 0 && ix1 < WID) ? 1.f : 0.f;
    float m10 = (iy1 >= 0 && iy1 < HH && ix0 >= 0 && ix0 < WID) ? 1.f : 0.f;
    float m11 = (iy1 >= 0 && iy1 < HH && ix1 >= 0 && ix1 < WID) ? 1.f : 0.f;
    int cy0 = min(max(iy0, 0), HH - 1), cy1 = min(max(iy1, 0), HH - 1);
    int cx0 = min(max(ix0, 0), WID - 1), cx1 = min(max(ix1, 0), WID - 1);
    size_t i00 = (size_t)(cy0 * WID + cx0) * 8, i01 = (size_t)(cy0 * WID + cx1) * 8;
    size_t i10 = (size_t)(cy1 * WID + cx0) * 8, i11 = (size_t)(cy1 * WID + cx1) * 8;
    C.r[0] = *(const half8v*)(xq0 + i00);  C.r[1] = *(const half8v*)(xq1 + i00);
    C.r[2] = *(const half8v*)(xq0 + i01);  C.r[3] = *(const half8v*)(xq1 + i01);
    C.r[4] = *(const half8v*)(xq0 + i10);  C.r[5] = *(const half8v*)(xq1 + i10);
    C.r[6] = *(const half8v*)(xq0 + i11);  C.r[7] = *(const half8v*)(xq1 + i11);
    C.w00 = (1.f - wy) * (1.f - wx) * m00;
    C.w01 = (1.f - wy) * wx * m01;
    C.w10 = wy * (1.f - wx) * m10;
    C.w11 = wy * wx * m11;
}

// packed fp16 bilinear combine: ~8 v_pk_fma_f16 per half8v
static __device__ inline void d_combine(const CornerRegs& C, half8v& f0, half8v& f1)
{
    half8v w00v = splat8((_Float16)C.w00);
    half8v w01v = splat8((_Float16)C.w01);
    half8v w10v = splat8((_Float16)C.w10);
    half8v w11v = splat8((_Float16)C.w11);
    f0 = C.r[0] * w00v + C.r[2] * w01v + C.r[4] * w10v + C.r[6] * w11v;
    f1 = C.r[1] * w00v + C.r[3] * w01v + C.r[5] * w10v + C.r[7] * w11v;
}

static __device__ inline void d_issue_conv(const _Float16* __restrict__ xq0,
                                           const _Float16* __restrict__ xq1,
                                           int y, int xg, int ki, int kj, int PAD,
                                           half8v& f0, half8v& f1)
{
    int gy = y + ki - PAD;
    int gx = xg + kj - PAD;
    bool ok = (gy >= 0 && gy < HH && gx >= 0 && gx < WID);
    if (ok) {
        size_t i = (size_t)(gy * WID + gx) * 8;
        f0 = *(const half8v*)(xq0 + i);
        f1 = *(const half8v*)(xq1 + i);
    } else {
        f0 = splat8((_Float16)0.f); f1 = splat8((_Float16)0.f);
    }
}

// ---------------------------------------------------------------------------
// Barrier-free wave-local MFMA conv, plane fp16 layout, NT pos-tiles per wave.
// Per-tap GEMM: D(o,pos) += W(o,c) * S(c,pos), MFMA 16x16x32 f16.
// Block = 4 waves x NT 16-pos tiles = 64*NT positions. A-frags (weights) are
// loaded once per tap per wave and reused across the NT tiles (amortized);
// tile j+1's corner loads are issued before tile j's combine (intra-tap ILP).
// DEFORM=true : bilinear sampling; out = plane-fp16 x tensor.
// DEFORM=false: shifted window;   out = tap-major float2 offset planes.
// ---------------------------------------------------------------------------
template<int K, int PAD, int NOT, int CO, int NT, bool DEFORM>
__global__ __launch_bounds__(256) void k_mconv(
    const _Float16* __restrict__ xin, const float* __restrict__ offp,
    const _Float16* __restrict__ wtb, const float* __restrict__ bias,
    void* __restrict__ outv)
{
    constexpr int KK = K * K;
    constexpr int OP = NOT * 16;
    constexpr int KTAP = CO / 2;                 // tap count of the offset consumer
    constexpr int BP = 64 * NT;                  // positions per block

    int p0  = blockIdx.x * BP;
    int b   = p0 / HW;
    int hwb = p0 % HW;

    int t    = threadIdx.x;
    int lane = t & 63;
    int wave = t >> 6;
    int p    = lane & 15;
    int q    = lane >> 4;
    int wlane = p * 8 + q;            // A-frag offset (half8 units)

    // per-tile coordinates
    int yt[NT], xt[NT], gp[NT];
#pragma unroll
    for (int j = 0; j < NT; j++) {
        int hwt = hwb + (wave * NT + j) * 16;
        yt[j] = hwt / WID;
        xt[j] = hwt % WID + p;
        gp[j] = p0 + (wave * NT + j) * 16 + p;
    }

    f32x4 acc[NT][NOT];
#pragma unroll
    for (int j = 0; j < NT; j++)
#pragma unroll
        for (int ot = 0; ot < NOT; ot++) acc[j][ot] = (f32x4){0.f, 0.f, 0.f, 0.f};

    const _Float16* xb  = xin + (size_t)b * HW * 64;
    const _Float16* xq0 = xb + (size_t)q * HW * 8;          // chunk-0 plane
    const _Float16* xq1 = xb + (size_t)(q + 4) * HW * 8;    // chunk-1 plane
    const half8v* wbase = (const half8v*)wtb;

    const float2* offj[NT];
    float2 offc[NT], offn[NT];
    if (DEFORM) {
#pragma unroll
        for (int j = 0; j < NT; j++) {
            offj[j] = (const float2*)offp + gp[j];
            offc[j] = offj[j][0];
        }
    }

    int ki = 0, kj = 0;
    for (int k = 0; k < KK; k++) {
        // prefetch next tap's offsets (plane k+1 <= KK exists: buffer has 50 planes)
        if (DEFORM) {
#pragma unroll
            for (int j = 0; j < NT; j++)
                offn[j] = offj[j][(size_t)(k + 1) * NPOS];
        }
        // this tap's A-frags, shared by all NT tiles
        const half8v* wp = wbase + (size_t)k * OP * 8;
        half8v aw0[NOT], aw1[NOT];
#pragma unroll
        for (int ot = 0; ot < NOT; ot++) {
            aw0[ot] = wp[ot * 128 + wlane];
            aw1[ot] = wp[ot * 128 + wlane + 4];
        }

        if (DEFORM) {
            CornerRegs CC[2];
            d_issue(xq0, xq1, yt[0], xt[0], ki, kj, PAD, offc[0], CC[0]);
#pragma unroll
            for (int j = 0; j < NT; j++) {
                if (j + 1 < NT)
                    d_issue(xq0, xq1, yt[j + 1], xt[j + 1], ki, kj, PAD, offc[j + 1], CC[(j + 1) & 1]);
                half8v f0, f1;
                d_combine(CC[j & 1], f0, f1);
#pragma unroll
                for (int ot = 0; ot < NOT; ot++)
                    acc[j][ot] = __builtin_amdgcn_mfma_f32_16x16x32_f16(aw0[ot], f0, acc[j][ot], 0, 0, 0);
#pragma unroll
                for (int ot = 0; ot < NOT; ot++)
                    acc[j][ot] = __builtin_amdgcn_mfma_f32_16x16x32_f16(aw1[ot], f1, acc[j][ot], 0, 0, 0);
            }
#pragma unroll
            for (int j = 0; j < NT; j++) offc[j] = offn[j];
        } else {
            half8v f0[NT], f1[NT];
#pragma unroll
            for (int j = 0; j < NT; j++)
                d_issue_conv(xq0, xq1, yt[j], xt[j], ki, kj, PAD, f0[j], f1[j]);
#pragma unroll
            for (int j = 0; j < NT; j++) {
#pragma unroll
                for (int ot = 0; ot < NOT; ot++)
                    acc[j][ot] = __builtin_amdgcn_mfma_f32_16x16x32_f16(aw0[ot], f0[j], acc[j][ot], 0, 0, 0);
#pragma unroll
                for (int ot = 0; ot < NOT; ot++)
                    acc[j][ot] = __builtin_amdgcn_mfma_f32_16x16x32_f16(aw1[ot], f1[j], acc[j][ot], 0, 0, 0);
            }
        }

        kj++;
        if (kj == K) { kj = 0; ki++; }
    }

    // ---- epilogue: D reg i -> o = ot*16 + q*4 + i, pos = gp[j] ----
    if (DEFORM) {
        _Float16* outp = (_Float16*)outv;
#pragma unroll
        for (int j = 0; j < NT; j++) {
            int hwp = hwb + (wave * NT + j) * 16 + p;
#pragma unroll
            for (int ot = 0; ot < NOT; ot++) {
                int ob = ot * 16 + q * 4;
                int plane = ob >> 3;
                int intra = ob & 7;
                float4 bb = *(const float4*)&bias[ob];
                half4v r;
                r[0] = (_Float16)(acc[j][ot][0] + bb.x);
                r[1] = (_Float16)(acc[j][ot][1] + bb.y);
                r[2] = (_Float16)(acc[j][ot][2] + bb.z);
                r[3] = (_Float16)(acc[j][ot][3] + bb.w);
                *(half4v*)&outp[(size_t)b * HW * 64 + (size_t)plane * HW * 8
                                + (size_t)hwp * 8 + intra] = r;
            }
        }
    } else {
        float* outf = (float*)outv;   // tap-major float2 planes
#pragma unroll
        for (int j = 0; j < NT; j++) {
#pragma unroll
            for (int ot = 0; ot < NOT; ot++) {
                int ob = ot * 16 + q * 4;     // channels ob..ob+3 = taps ob/2, ob/2+1
                int t0 = ob >> 1;
                if (t0 < KTAP) {
                    float2 r; r.x = acc[j][ot][0] + bias[ob];     r.y = acc[j][ot][1] + bias[ob + 1];
                    *(float2*)&outf[((size_t)t0 * NPOS + gp[j]) * 2] = r;
                }
                if (t0 + 1 < KTAP) {
                    float2 r; r.x = acc[j][ot][2] + bias[ob + 2]; r.y = acc[j][ot][3] + bias[ob + 3];
                    *(float2*)&outf[((size_t)(t0 + 1) * NPOS + gp[j]) * 2] = r;
                }
            }
        }
    }
}

// ---------------------------------------------------------------------------
// K4: h = x1_final + x2 (plane fp16); out = h @ w_out^T + b_out + x (NCHW fp32)
// ---------------------------------------------------------------------------
__global__ __launch_bounds__(256) void k_merge_out(
    const _Float16* __restrict__ x1f, const _Float16* __restrict__ x2,
    const float* __restrict__ xin, const float* __restrict__ w_out,
    const float* __restrict__ b_out, float* __restrict__ out)
{
    int p  = blockIdx.x * 256 + threadIdx.x;
    int b  = p / HW;
    int hw = p % HW;

    const _Float16* a1 = x1f + (size_t)b * HW * 64 + (size_t)hw * 8;
    const _Float16* a2 = x2  + (size_t)b * HW * 64 + (size_t)hw * 8;
    float v[64];
#pragma unroll
    for (int pl = 0; pl < 8; pl++) {
        half8v u1 = *(const half8v*)&a1[(size_t)pl * HW * 8];
        half8v u2 = *(const half8v*)&a2[(size_t)pl * HW * 8];
#pragma unroll
        for (int j = 0; j < 8; j++)
            v[pl * 8 + j] = (float)u1[j] + (float)u2[j];
    }

    size_t base = (size_t)b * CB * HW + hw;
    for (int o = 0; o < 64; o++) {
        float a = b_out[o] + xin[base + (size_t)o * HW];
#pragma unroll
        for (int c = 0; c < 64; c++) a += v[c] * w_out[o * 64 + c];
        out[base + (size_t)o * HW] = a;
    }
}

// ---------------------------------------------------------------------------
// Launch. Workspace: x1a/x1b/x2 plane fp16 (18.9 MB each), off tap-major
// float2 planes (50 planes * NPOS * 8B = 59 MB), fp16 weights (~1.3 MB).
// ---------------------------------------------------------------------------
extern "C" void kernel_launch(void* const* d_in, const int* in_sizes, int n_in,
                              void* d_out, int out_size, void* d_ws, size_t ws_size,
                              hipStream_t stream)
{
    const float* x     = (const float*)d_in[0];
    const float* ln_w  = (const float*)d_in[1];
    const float* ln_b  = (const float*)d_in[2];
    const float* w_in  = (const float*)d_in[3];
    const float* b_in  = (const float*)d_in[4];
    const float* w_out = (const float*)d_in[5];
    const float* b_out = (const float*)d_in[6];
    const float* dw1   = (const float*)d_in[7];
    const float* db1   = (const float*)d_in[8];
    const float* dw2   = (const float*)d_in[9];
    const float* db2   = (const float*)d_in[10];
    const float* dw3   = (const float*)d_in[11];
    const float* db3   = (const float*)d_in[12];
    const float* ow1   = (const float*)d_in[13];
    const float* ob1   = (const float*)d_in[14];
    const float* ow2   = (const float*)d_in[15];
    const float* ob2   = (const float*)d_in[16];
    const float* ow3   = (const float*)d_in[17];
    const float* ob3   = (const float*)d_in[18];

    _Float16* x1a = (_Float16*)d_ws;
    _Float16* x1b = x1a + (size_t)NPOS * 64;
    _Float16* x2  = x1b + (size_t)NPOS * 64;
    float* off = (float*)(x2 + (size_t)NPOS * 64);
    _Float16* wtd1 = (_Float16*)(off + (size_t)NPOS * 100);
    _Float16* wtd2 = wtd1 + 49 * 64 * 64;
    _Float16* wtd3 = wtd2 + 25 * 64 * 64;
    _Float16* wto1 = wtd3 +  9 * 64 * 64;
    _Float16* wto2 = wto1 + 25 * 112 * 64;
    _Float16* wto3 = wto2 + 25 * 64 * 64;

    // weight prep (fp16, [tap][o][c])
    k_wth<49, 64,  64><<<784, 256, 0, stream>>>(dw1, wtd1);
    k_wth<25, 64,  64><<<400, 256, 0, stream>>>(dw2, wtd2);
    k_wth< 9, 64,  64><<<144, 256, 0, stream>>>(dw3, wtd3);
    k_wth<25, 98, 112><<<700, 256, 0, stream>>>(ow1, wto1);
    k_wth<25, 50,  64><<<400, 256, 0, stream>>>(ow2, wto2);
    k_wth< 9, 18,  32><<< 72, 256, 0, stream>>>(ow3, wto3);

    k_ln_conv_in<<<NPOS / 256, 256, 0, stream>>>(x, ln_w, ln_b, w_in, b_in, x1a, x2);

    // NT=2: block = 128 positions, grid = NPOS/128 = 1152
    // stage 1
    k_mconv<5, 2, 7, 98, 2, false><<<1152, 256, 0, stream>>>(x1a, off, wto1, ob1, off);
    k_mconv<7, 3, 4, 64, 2, true ><<<1152, 256, 0, stream>>>(x1a, off, wtd1, db1, x1b);
    // stage 2
    k_mconv<5, 2, 4, 50, 2, false><<<1152, 256, 0, stream>>>(x1b, off, wto2, ob2, off);
    k_mconv<5, 2, 4, 64, 2, true ><<<1152, 256, 0, stream>>>(x1b, off, wtd2, db2, x1a);
    // stage 3
    k_mconv<3, 1, 2, 18, 2, false><<<1152, 256, 0, stream>>>(x1a, off, wto3, ob3, off);
    k_mconv<3, 1, 4, 64, 2, true ><<<1152, 256, 0, stream>>>(x1a, off, wtd3, db3, x1b);

    k_merge_out<<<NPOS / 256, 256, 0, stream>>>(x1b, x2, x, w_out, b_out, (float*)d_out);
}